// Round 7
// baseline (494.676 us; speedup 1.0000x reference)
//
#include <hip/hip_runtime.h>
#include <math.h>

// ---------------------------------------------------------------------------
// GAT pipeline (R7):
//   wsplit + CSR build  [once per launch]
//   per layer: split-bf16 MFMA GEMM (fused attn stats, bf16 xl out)
//              -> alpha_kernel (per-node online softmax -> ealpha[h][e])
//              -> gather_kernel: XCD-channel-sliced L2-resident gather
//   mean pool -> 2-layer MLP -> scalar out
// R4-R6 post-mortem: agg pinned at 55-64us, FETCH 149MB @ ~3.3TB/s for all
//   ILP/occupancy variants -> L2-capacity-bound (xl=20MB vs 4MB/XCD L2).
// R7: slice gather by 64-ch (slice = blockIdx % 8 -> one slice per XCD,
//   2.5MB fits L2); alpha hoisted to its own kernel (no 8x duplication);
//   2 edges/load-inst via lane-halving; nt loads on streams.
// ---------------------------------------------------------------------------

typedef float f32x4 __attribute__((ext_vector_type(4)));
typedef short s16x8 __attribute__((ext_vector_type(8)));
typedef short s16x4 __attribute__((ext_vector_type(4)));

__device__ inline ushort f2bf(float f) {
  unsigned u = __float_as_uint(f);
  u += 0x7FFF + ((u >> 16) & 1);          // round-to-nearest-even
  return (ushort)(u >> 16);
}
__device__ inline float bf2f(ushort h) { return __uint_as_float((unsigned)h << 16); }

// ---------------- CSR build ----------------
__global__ void count_kernel(const int* __restrict__ ei, int* __restrict__ counts,
                             int E, int n) {
  int t = blockIdx.x * blockDim.x + threadIdx.x;
  if (t < E) {
    atomicAdd(&counts[ei[E + t]], 1);          // dst row of edge_index
  } else if (t < E + n) {
    atomicAdd(&counts[t - E], 1);              // self loop
  }
}

__global__ void scan1_kernel(const int* __restrict__ counts, int* __restrict__ partials,
                             int n) {
  __shared__ int sd[4];
  int i = blockIdx.x * 256 + threadIdx.x;
  int v = (i < n) ? counts[i] : 0;
  for (int m = 32; m; m >>= 1) v += __shfl_xor(v, m);
  if ((threadIdx.x & 63) == 0) sd[threadIdx.x >> 6] = v;
  __syncthreads();
  if (threadIdx.x == 0) partials[blockIdx.x] = sd[0] + sd[1] + sd[2] + sd[3];
}

__global__ void scan2_kernel(int* __restrict__ partials, int nb) {
  __shared__ int sd[1024];
  int t = threadIdx.x;
  int v = (t < nb) ? partials[t] : 0;
  sd[t] = v;
  __syncthreads();
  for (int off = 1; off < 1024; off <<= 1) {
    int u = (t >= off) ? sd[t - off] : 0;
    __syncthreads();
    sd[t] += u;
    __syncthreads();
  }
  if (t < nb) partials[t] = sd[t] - v;
}

__global__ void scan3_kernel(const int* __restrict__ counts, const int* __restrict__ partials,
                             int* __restrict__ offsets, int n) {
  __shared__ int sd[256];
  int i = blockIdx.x * 256 + threadIdx.x;
  int t = threadIdx.x;
  int v = (i < n) ? counts[i] : 0;
  sd[t] = v;
  __syncthreads();
  for (int off = 1; off < 256; off <<= 1) {
    int u = (t >= off) ? sd[t - off] : 0;
    __syncthreads();
    sd[t] += u;
    __syncthreads();
  }
  int carry = partials[blockIdx.x];
  if (i < n) {
    offsets[i] = carry + sd[t] - v;
    if (i == n - 1) offsets[n] = carry + sd[t];
  }
}

__global__ void scatter_kernel(const int* __restrict__ ei, const int* __restrict__ offsets,
                               int* __restrict__ cursor, int* __restrict__ srcs,
                               int E, int n) {
  int t = blockIdx.x * blockDim.x + threadIdx.x;
  int s, d;
  if (t < E)          { s = ei[t]; d = ei[E + t]; }
  else if (t < E + n) { s = t - E; d = s; }
  else return;
  int pos = offsets[d] + atomicAdd(&cursor[d], 1);
  srcs[pos] = s;
}

// ------- weight transpose + bf16 split for all 3 layers in one launch -------
__global__ void wsplit_all_kernel(
    const float* __restrict__ W0, const float* __restrict__ W1,
    const float* __restrict__ W2, ushort* __restrict__ w0h, ushort* __restrict__ w0l,
    ushort* __restrict__ w1h, ushort* __restrict__ w1l, ushort* __restrict__ w2h,
    ushort* __restrict__ w2l) {
  int idx = blockIdx.x * 256 + threadIdx.x;
  const float* W; ushort *th, *tl; int K, N;
  if (idx < 16384)      { W = W0; th = w0h; tl = w0l; K = 128; N = 512; }
  else if (idx < 81920) { idx -= 16384; W = W1; th = w1h; tl = w1l; K = 512; N = 512; }
  else if (idx < 98304) { idx -= 81920; W = W2; th = w2h; tl = w2l; K = 512; N = 128; }
  else return;
  int n = idx % N;
  int k4 = (idx / N) << 2;
  s16x4 hv, lv;
#pragma unroll
  for (int r = 0; r < 4; ++r) {
    float w = W[(size_t)(k4 + r) * N + n];
    ushort h = f2bf(w);
    hv[r] = (short)h;
    lv[r] = (short)f2bf(w - bf2f(h));
  }
  *(s16x4*)&th[(size_t)n * K + k4] = hv;
  *(s16x4*)&tl[(size_t)n * K + k4] = lv;
}

// ---------------- split-bf16 MFMA GEMM + fused per-head attn stats ----------
__global__ __launch_bounds__(256, 2) void gemm_mfma_kernel(
    const float* __restrict__ A, const ushort* __restrict__ Bth,
    const ushort* __restrict__ Btl, ushort* __restrict__ Cb,
    const float* __restrict__ a_s, const float* __restrict__ a_d,
    float* __restrict__ asn, float* __restrict__ adn,
    int M, int K, int N, int H) {
  __shared__ ushort Ash[64][40], Asl[64][40];
  __shared__ ushort Bsh[128][40], Bsl[128][40];
  __shared__ float st_sh[2][64][2];
  int tid = threadIdx.x;
  int row0 = blockIdx.y * 64, col0 = blockIdx.x * 128;
  int hidx = blockIdx.x;
  int am = tid >> 2, ak = (tid & 3) << 3;
  int bn = tid >> 1, bk = (tid & 1) << 4;
  int lane = tid & 63, wid = tid >> 6;
  int wm = (wid & 1) << 5, wn = (wid >> 1) << 6;
  int fr = lane & 15, fq = (lane >> 4) << 3;
  f32x4 acc[2][4] = {};
  const float* Arow = A + (size_t)(row0 + am) * K;
  bool avalid = (row0 + am) < M;
  const ushort* bhp = Bth + (size_t)(col0 + bn) * K + bk;
  const ushort* blp = Btl + (size_t)(col0 + bn) * K + bk;

  for (int k0 = 0; k0 < K; k0 += 32) {
    float v[8];
    if (avalid) {
      float4 t0 = *(const float4*)(Arow + k0 + ak);
      float4 t1 = *(const float4*)(Arow + k0 + ak + 4);
      v[0] = t0.x; v[1] = t0.y; v[2] = t0.z; v[3] = t0.w;
      v[4] = t1.x; v[5] = t1.y; v[6] = t1.z; v[7] = t1.w;
    } else {
#pragma unroll
      for (int r = 0; r < 8; ++r) v[r] = 0.f;
    }
    s16x8 hv, lv;
#pragma unroll
    for (int r = 0; r < 8; ++r) {
      ushort h = f2bf(v[r]);
      hv[r] = (short)h;
      lv[r] = (short)f2bf(v[r] - bf2f(h));
    }
    *(s16x8*)&Ash[am][ak] = hv;
    *(s16x8*)&Asl[am][ak] = lv;
    *(s16x8*)&Bsh[bn][bk]     = *(const s16x8*)(bhp + k0);
    *(s16x8*)&Bsh[bn][bk + 8] = *(const s16x8*)(bhp + k0 + 8);
    *(s16x8*)&Bsl[bn][bk]     = *(const s16x8*)(blp + k0);
    *(s16x8*)&Bsl[bn][bk + 8] = *(const s16x8*)(blp + k0 + 8);
    __syncthreads();
    s16x8 ah[2], al[2], bh[4], bl[4];
#pragma unroll
    for (int i = 0; i < 2; ++i) {
      ah[i] = *(const s16x8*)&Ash[wm + i * 16 + fr][fq];
      al[i] = *(const s16x8*)&Asl[wm + i * 16 + fr][fq];
    }
#pragma unroll
    for (int j = 0; j < 4; ++j) {
      bh[j] = *(const s16x8*)&Bsh[wn + j * 16 + fr][fq];
      bl[j] = *(const s16x8*)&Bsl[wn + j * 16 + fr][fq];
    }
#pragma unroll
    for (int i = 0; i < 2; ++i)
#pragma unroll
      for (int j = 0; j < 4; ++j) {
        acc[i][j] = __builtin_amdgcn_mfma_f32_16x16x32_bf16(ah[i], bh[j], acc[i][j], 0, 0, 0);
        acc[i][j] = __builtin_amdgcn_mfma_f32_16x16x32_bf16(ah[i], bl[j], acc[i][j], 0, 0, 0);
        acc[i][j] = __builtin_amdgcn_mfma_f32_16x16x32_bf16(al[i], bh[j], acc[i][j], 0, 0, 0);
      }
    __syncthreads();
  }
  float asv[4], adv[4];
#pragma unroll
  for (int j = 0; j < 4; ++j) {
    asv[j] = a_s[hidx * 128 + wn + j * 16 + fr];
    adv[j] = a_d[hidx * 128 + wn + j * 16 + fr];
  }
  int rb = row0 + wm + ((lane >> 4) << 2);
  int cb = col0 + wn + fr;
#pragma unroll
  for (int i = 0; i < 2; ++i)
#pragma unroll
    for (int r = 0; r < 4; ++r) {
      int row = rb + i * 16 + r;
      float sp = 0.f, dp = 0.f;
#pragma unroll
      for (int j = 0; j < 4; ++j) {
        float c = acc[i][j][r];
        sp += c * asv[j];
        dp += c * adv[j];
        if (row < M) Cb[(size_t)row * N + cb + j * 16] = f2bf(c);
      }
#pragma unroll
      for (int m = 1; m < 16; m <<= 1) {
        sp += __shfl_xor(sp, m);
        dp += __shfl_xor(dp, m);
      }
      if ((lane & 15) == 0) {
        int rowb = wm + i * 16 + ((lane >> 4) << 2) + r;
        st_sh[0][rowb][wid >> 1] = sp;
        st_sh[1][rowb][wid >> 1] = dp;
      }
    }
  __syncthreads();
  if (tid < 64) {
    int row = row0 + tid;
    if (row < M) {
      asn[(size_t)row * H + hidx] = st_sh[0][tid][0] + st_sh[0][tid][1];
      adn[(size_t)row * H + hidx] = st_sh[1][tid][0] + st_sh[1][tid][1];
    }
  }
}

// ------- alpha: per-node online softmax -> ealpha_t[h*ET + e] (fp32) -------
template <int H>
__global__ __launch_bounds__(256) void alpha_kernel(
    const float* __restrict__ asn, const float* __restrict__ adn,
    const int* __restrict__ offsets, const int* __restrict__ srcs,
    float* __restrict__ ealpha_t, int n, int ET) {
  int wib = threadIdx.x >> 6;
  int lane = threadIdx.x & 63;
  int nd = blockIdx.x * 4 + wib;
  if (nd >= n) return;
  int beg = offsets[nd];
  int deg = offsets[nd + 1] - beg;
  float adl[H];
#pragma unroll
  for (int h = 0; h < H; ++h) adl[h] = adn[(size_t)nd * H + h];

  float mh[H], lh[H];
#pragma unroll
  for (int h = 0; h < H; ++h) { mh[h] = -3.0e38f; lh[h] = 0.f; }
  for (int j0 = 0; j0 < deg; j0 += 64) {
    int j = j0 + lane;
    if (j < deg) {
      int s = srcs[beg + j];
      float ev[H];
      if constexpr (H == 4) {
        float4 av = *(const float4*)&asn[(size_t)s * 4];
        ev[0] = av.x; ev[1] = av.y; ev[2] = av.z; ev[3] = av.w;
      } else {
        ev[0] = asn[s];
      }
#pragma unroll
      for (int h = 0; h < H; ++h) {
        float e = ev[h] + adl[h];
        e = (e > 0.f) ? e : 0.2f * e;
        float mn = fmaxf(mh[h], e);
        lh[h] = lh[h] * __expf(mh[h] - mn) + __expf(e - mn);
        mh[h] = mn;
      }
    }
  }
#pragma unroll
  for (int h = 0; h < H; ++h) {
    for (int m = 1; m < 64; m <<= 1) {
      float mo = __shfl_xor(mh[h], m);
      float lo = __shfl_xor(lh[h], m);
      float mn = fmaxf(mh[h], mo);
      lh[h] = lh[h] * __expf(mh[h] - mn) + lo * __expf(mo - mn);
      mh[h] = mn;
    }
    lh[h] = 1.f / lh[h];               // 1/den
  }
  for (int j0 = 0; j0 < deg; j0 += 64) {
    int j = j0 + lane;
    if (j < deg) {
      int s = srcs[beg + j];
      float ev[H];
      if constexpr (H == 4) {
        float4 av = *(const float4*)&asn[(size_t)s * 4];
        ev[0] = av.x; ev[1] = av.y; ev[2] = av.z; ev[3] = av.w;
      } else {
        ev[0] = asn[s];
      }
#pragma unroll
      for (int h = 0; h < H; ++h) {
        float e = ev[h] + adl[h];
        e = (e > 0.f) ? e : 0.2f * e;
        ealpha_t[(size_t)h * ET + beg + j] = __expf(e - mh[h]) * lh[h];
      }
    }
  }
}

// ------- XCD-channel-sliced gather: out[:, slice*64 : slice*64+64] -------
// slice = blockIdx % NS (residue-class -> one slice per XCD); wave = 1 node.
// Lanes 0-31 process edge j, lanes 32-63 edge j+1; 2 ch/lane (uint bf16x2).
template <int HC, int NS, bool RELU>
__global__ __launch_bounds__(256) void gather_kernel(
    const ushort* __restrict__ xl, const float* __restrict__ ealpha_t,
    const int* __restrict__ offsets, const int* __restrict__ srcs,
    const float* __restrict__ bias, float* __restrict__ out, int n, int ET) {
  __shared__ int src_sh[4][64];
  __shared__ float a_sh[4][64];
  int wib = threadIdx.x >> 6;
  int lane = threadIdx.x & 63;
  int slice = blockIdx.x % NS;
  int nd = (blockIdx.x / NS) * 4 + wib;
  if (nd >= n) return;
  int ch0 = slice << 6;                       // 64 channels per slice
  int head = (HC == 512) ? (slice >> 1) : 0;  // 128 ch per head
  int beg = offsets[nd];
  int deg = offsets[nd + 1] - beg;
  int half = lane >> 5;                       // 0: even edge, 1: odd edge
  int chl = (lane & 31) << 1;                 // my 2 channels in slice
  const float* alp = ealpha_t + (size_t)head * ET + beg;
  const ushort* xlc = xl + ch0 + chl;
  float2 bv = *(const float2*)&bias[ch0 + chl];

  float acc0 = 0.f, acc1 = 0.f;
  for (int j0 = 0; j0 < deg; j0 += 64) {
    int j = j0 + lane;
    int s = 0; float a = 0.f;
    if (j < deg) {
      s = __builtin_nontemporal_load(&srcs[beg + j]);
      a = __builtin_nontemporal_load(&alp[j]);
    }
    src_sh[wib][lane] = s;
    a_sh[wib][lane] = a;                      // dummy edges: a=0, s=0 (harmless)
    __builtin_amdgcn_wave_barrier();
    int cl4 = (min(64, deg - j0) + 3) & ~3;
    for (int jj = 0; jj < cl4; jj += 4) {
      int s0 = src_sh[wib][jj + half];
      int s1 = src_sh[wib][jj + 2 + half];
      float a0 = a_sh[wib][jj + half];
      float a1 = a_sh[wib][jj + 2 + half];
      uint v0 = *(const uint*)(xlc + (size_t)s0 * HC);
      uint v1 = *(const uint*)(xlc + (size_t)s1 * HC);
      acc0 += a0 * bf2f((ushort)(v0 & 0xFFFF));
      acc1 += a0 * bf2f((ushort)(v0 >> 16));
      acc0 += a1 * bf2f((ushort)(v1 & 0xFFFF));
      acc1 += a1 * bf2f((ushort)(v1 >> 16));
    }
    __builtin_amdgcn_wave_barrier();
  }
  // merge edge-halves (lanes l and l+32 hold same channels)
  acc0 += __shfl_xor(acc0, 32);
  acc1 += __shfl_xor(acc1, 32);
  if (half == 0) {
    float2 o;
    o.x = acc0 + bv.x;
    o.y = acc1 + bv.y;
    if (RELU) { o.x = fmaxf(o.x, 0.f); o.y = fmaxf(o.y, 0.f); }
    *(float2*)(out + (size_t)nd * HC + ch0 + chl) = o;
  }
}

// ---------------- mean pool (partial sums + atomics) ----------------
__global__ void pool_kernel(const float* __restrict__ h, float* __restrict__ g, int n) {
  int c = threadIdx.x;                 // 128 threads
  float acc = 0.f;
  for (int r = blockIdx.x; r < n; r += gridDim.x) acc += h[(size_t)r * 128 + c];
  atomicAdd(&g[c], acc);
}

// ---------------- final MLP ----------------
__global__ void mlp_kernel(const float* __restrict__ g, const float* __restrict__ Wm1,
                           const float* __restrict__ bm1, const float* __restrict__ Wm2,
                           const float* __restrict__ bm2, float* __restrict__ out,
                           float invn) {
  __shared__ float gs[128];
  __shared__ float hs[64];
  int t = threadIdx.x;                 // 64 threads
  gs[t] = g[t] * invn;
  gs[t + 64] = g[t + 64] * invn;
  __syncthreads();
  float acc = bm1[t];
  for (int c = 0; c < 128; ++c) acc += gs[c] * Wm1[c * 64 + t];
  hs[t] = fmaxf(acc, 0.f);
  __syncthreads();
  if (t == 0) {
    float o = bm2[0];
    for (int j = 0; j < 64; ++j) o += hs[j] * Wm2[j];
    out[0] = o;
  }
}

// ---------------------------------------------------------------------------
extern "C" void kernel_launch(void* const* d_in, const int* in_sizes, int n_in,
                              void* d_out, int out_size, void* d_ws, size_t ws_size,
                              hipStream_t stream) {
  const float* x   = (const float*)d_in[0];
  const int*   ei  = (const int*)d_in[1];
  const float* W0  = (const float*)d_in[2];
  const float* as0 = (const float*)d_in[3];
  const float* ad0 = (const float*)d_in[4];
  const float* b0  = (const float*)d_in[5];
  const float* W1  = (const float*)d_in[6];
  const float* as1 = (const float*)d_in[7];
  const float* ad1 = (const float*)d_in[8];
  const float* b1  = (const float*)d_in[9];
  const float* W2  = (const float*)d_in[10];
  const float* as2 = (const float*)d_in[11];
  const float* ad2 = (const float*)d_in[12];
  const float* b2  = (const float*)d_in[13];
  const float* Wm1 = (const float*)d_in[14];
  const float* bm1 = (const float*)d_in[15];
  const float* Wm2 = (const float*)d_in[16];
  const float* bm2 = (const float*)d_in[17];

  const int N = in_sizes[0] / 128;     // 20000
  const int E = in_sizes[1] / 2;       // 320000
  const int ET = E + N;                // with self loops

  // workspace layout
  float*  Bb  = (float*)d_ws;                     // N*512 fp32
  ushort* xlb = (ushort*)(Bb + (size_t)N * 512);  // N*512 bf16 xl
  float*  asn = (float*)(xlb + (size_t)N * 512);  // N*4
  float*  adn = asn + (size_t)N * 4;              // N*4
  float*  g   = adn + (size_t)N * 4;              // 128 pool accumulator
  int* counts = (int*)(g + 128);                  // N
  int* cursor = counts + N;                       // N
  int* offs   = cursor + N;                       // N+1
  int* srcs   = offs + N + 1;                     // ET
  int* parts  = srcs + ET;                        // 1024 scan partials
  float* ealpha = (float*)(parts + 1024);         // 4*ET (transposed [h][e])
  ushort* w0h = (ushort*)(((uintptr_t)(ealpha + (size_t)4 * ET) + 63) & ~(uintptr_t)63);
  ushort* w0l = w0h + 512 * 128;
  ushort* w1h = w0l + 512 * 128;
  ushort* w1l = w1h + 512 * 512;
  ushort* w2h = w1l + 512 * 512;
  ushort* w2l = w2h + 128 * 512;

  // zero pool accumulator + counts + cursor (contiguous)
  hipMemsetAsync(g, 0, (size_t)(128 + 2 * N) * sizeof(int), stream);

  wsplit_all_kernel<<<(98304 + 255) / 256, 256, 0, stream>>>(
      W0, W1, W2, w0h, w0l, w1h, w1l, w2h, w2l);

  // CSR by dst (multi-block scan)
  int ebl = (ET + 255) / 256;
  int nb = (N + 255) / 256;
  count_kernel<<<ebl, 256, 0, stream>>>(ei, counts, E, N);
  scan1_kernel<<<nb, 256, 0, stream>>>(counts, parts, N);
  scan2_kernel<<<1, 1024, 0, stream>>>(parts, nb);
  scan3_kernel<<<nb, 256, 0, stream>>>(counts, parts, offs, N);
  scatter_kernel<<<ebl, 256, 0, stream>>>(ei, offs, cursor, srcs, E, N);

  int nwb4 = (N + 3) / 4;              // 4 nodes/block kernels
  dim3 gG01(4, (N + 63) / 64);
  dim3 gG2(1, (N + 63) / 64);
  int gather4_grid = 8 * nwb4;         // 8 slices x node-blocks
  int gather1_grid = 2 * nwb4;         // 2 slices

  // layer 0
  gemm_mfma_kernel<<<gG01, 256, 0, stream>>>(x, w0h, w0l, xlb, as0, ad0, asn, adn,
                                             N, 128, 512, 4);
  alpha_kernel<4><<<nwb4, 256, 0, stream>>>(asn, adn, offs, srcs, ealpha, N, ET);
  gather_kernel<512, 8, true><<<gather4_grid, 256, 0, stream>>>(
      xlb, ealpha, offs, srcs, b0, Bb, N, ET);

  // layer 1
  gemm_mfma_kernel<<<gG01, 256, 0, stream>>>(Bb, w1h, w1l, xlb, as1, ad1, asn, adn,
                                             N, 512, 512, 4);
  alpha_kernel<4><<<nwb4, 256, 0, stream>>>(asn, adn, offs, srcs, ealpha, N, ET);
  gather_kernel<512, 8, true><<<gather4_grid, 256, 0, stream>>>(
      xlb, ealpha, offs, srcs, b1, Bb, N, ET);

  // layer 2 (1 head, no relu)
  gemm_mfma_kernel<<<gG2, 256, 0, stream>>>(Bb, w2h, w2l, xlb, as2, ad2, asn, adn,
                                            N, 512, 128, 1);
  alpha_kernel<1><<<nwb4, 256, 0, stream>>>(asn, adn, offs, srcs, ealpha, N, ET);
  gather_kernel<128, 2, false><<<gather1_grid, 256, 0, stream>>>(
      xlb, ealpha, offs, srcs, b2, Bb, N, ET);

  // mean pool + MLP
  pool_kernel<<<128, 128, 0, stream>>>(Bb, g, N);
  mlp_kernel<<<1, 64, 0, stream>>>(g, Wm1, bm1, Wm2, bm2, (float*)d_out, 1.0f / (float)N);
}

// Round 8
// 388.129 us; speedup vs baseline: 1.2745x; 1.2745x over previous
//
#include <hip/hip_runtime.h>
#include <math.h>

// ---------------------------------------------------------------------------
// GAT pipeline (R8):
//   wsplit + CSR build  [once per launch]
//   per layer: split-bf16 MFMA GEMM (fused attn stats, bf16 xl out)
//              -> single-pass agg: unnormalized exp-weighted gather + den,
//                 divide at end (no softmax-max pass; |e|<~6 by construction)
//   mean pool -> 2-layer MLP -> scalar out
// R7 post-mortem: channel-slicing made gather L2-resident (FETCH 149->21MB)
//   but 8x control-work + 4B loads regressed 64->78us. Revert to R4 16B-load
//   structure; optimize instruction count instead.
// R8: one edge sweep total (exp without max is safe: logits bounded ~6),
//   int4/float4 LDS index+alpha reads, 4-edge load batch (16 VGPRs).
// ---------------------------------------------------------------------------

typedef float f32x4 __attribute__((ext_vector_type(4)));
typedef short s16x8 __attribute__((ext_vector_type(8)));
typedef short s16x4 __attribute__((ext_vector_type(4)));

__device__ inline ushort f2bf(float f) {
  unsigned u = __float_as_uint(f);
  u += 0x7FFF + ((u >> 16) & 1);          // round-to-nearest-even
  return (ushort)(u >> 16);
}
__device__ inline float bf2f(ushort h) { return __uint_as_float((unsigned)h << 16); }

// ---------------- CSR build ----------------
__global__ void count_kernel(const int* __restrict__ ei, int* __restrict__ counts,
                             int E, int n) {
  int t = blockIdx.x * blockDim.x + threadIdx.x;
  if (t < E) {
    atomicAdd(&counts[ei[E + t]], 1);          // dst row of edge_index
  } else if (t < E + n) {
    atomicAdd(&counts[t - E], 1);              // self loop
  }
}

__global__ void scan1_kernel(const int* __restrict__ counts, int* __restrict__ partials,
                             int n) {
  __shared__ int sd[4];
  int i = blockIdx.x * 256 + threadIdx.x;
  int v = (i < n) ? counts[i] : 0;
  for (int m = 32; m; m >>= 1) v += __shfl_xor(v, m);
  if ((threadIdx.x & 63) == 0) sd[threadIdx.x >> 6] = v;
  __syncthreads();
  if (threadIdx.x == 0) partials[blockIdx.x] = sd[0] + sd[1] + sd[2] + sd[3];
}

__global__ void scan2_kernel(int* __restrict__ partials, int nb) {
  __shared__ int sd[1024];
  int t = threadIdx.x;
  int v = (t < nb) ? partials[t] : 0;
  sd[t] = v;
  __syncthreads();
  for (int off = 1; off < 1024; off <<= 1) {
    int u = (t >= off) ? sd[t - off] : 0;
    __syncthreads();
    sd[t] += u;
    __syncthreads();
  }
  if (t < nb) partials[t] = sd[t] - v;
}

__global__ void scan3_kernel(const int* __restrict__ counts, const int* __restrict__ partials,
                             int* __restrict__ offsets, int n) {
  __shared__ int sd[256];
  int i = blockIdx.x * 256 + threadIdx.x;
  int t = threadIdx.x;
  int v = (i < n) ? counts[i] : 0;
  sd[t] = v;
  __syncthreads();
  for (int off = 1; off < 256; off <<= 1) {
    int u = (t >= off) ? sd[t - off] : 0;
    __syncthreads();
    sd[t] += u;
    __syncthreads();
  }
  int carry = partials[blockIdx.x];
  if (i < n) {
    offsets[i] = carry + sd[t] - v;
    if (i == n - 1) offsets[n] = carry + sd[t];
  }
}

__global__ void scatter_kernel(const int* __restrict__ ei, const int* __restrict__ offsets,
                               int* __restrict__ cursor, int* __restrict__ srcs,
                               int E, int n) {
  int t = blockIdx.x * blockDim.x + threadIdx.x;
  int s, d;
  if (t < E)          { s = ei[t]; d = ei[E + t]; }
  else if (t < E + n) { s = t - E; d = s; }
  else return;
  int pos = offsets[d] + atomicAdd(&cursor[d], 1);
  srcs[pos] = s;
}

// ------- weight transpose + bf16 split for all 3 layers in one launch -------
__global__ void wsplit_all_kernel(
    const float* __restrict__ W0, const float* __restrict__ W1,
    const float* __restrict__ W2, ushort* __restrict__ w0h, ushort* __restrict__ w0l,
    ushort* __restrict__ w1h, ushort* __restrict__ w1l, ushort* __restrict__ w2h,
    ushort* __restrict__ w2l) {
  int idx = blockIdx.x * 256 + threadIdx.x;
  const float* W; ushort *th, *tl; int K, N;
  if (idx < 16384)      { W = W0; th = w0h; tl = w0l; K = 128; N = 512; }
  else if (idx < 81920) { idx -= 16384; W = W1; th = w1h; tl = w1l; K = 512; N = 512; }
  else if (idx < 98304) { idx -= 81920; W = W2; th = w2h; tl = w2l; K = 512; N = 128; }
  else return;
  int n = idx % N;
  int k4 = (idx / N) << 2;
  s16x4 hv, lv;
#pragma unroll
  for (int r = 0; r < 4; ++r) {
    float w = W[(size_t)(k4 + r) * N + n];
    ushort h = f2bf(w);
    hv[r] = (short)h;
    lv[r] = (short)f2bf(w - bf2f(h));
  }
  *(s16x4*)&th[(size_t)n * K + k4] = hv;
  *(s16x4*)&tl[(size_t)n * K + k4] = lv;
}

// ---------------- split-bf16 MFMA GEMM + fused per-head attn stats ----------
__global__ __launch_bounds__(256, 2) void gemm_mfma_kernel(
    const float* __restrict__ A, const ushort* __restrict__ Bth,
    const ushort* __restrict__ Btl, ushort* __restrict__ Cb,
    const float* __restrict__ a_s, const float* __restrict__ a_d,
    float* __restrict__ asn, float* __restrict__ adn,
    int M, int K, int N, int H) {
  __shared__ ushort Ash[64][40], Asl[64][40];
  __shared__ ushort Bsh[128][40], Bsl[128][40];
  __shared__ float st_sh[2][64][2];
  int tid = threadIdx.x;
  int row0 = blockIdx.y * 64, col0 = blockIdx.x * 128;
  int hidx = blockIdx.x;
  int am = tid >> 2, ak = (tid & 3) << 3;
  int bn = tid >> 1, bk = (tid & 1) << 4;
  int lane = tid & 63, wid = tid >> 6;
  int wm = (wid & 1) << 5, wn = (wid >> 1) << 6;
  int fr = lane & 15, fq = (lane >> 4) << 3;
  f32x4 acc[2][4] = {};
  const float* Arow = A + (size_t)(row0 + am) * K;
  bool avalid = (row0 + am) < M;
  const ushort* bhp = Bth + (size_t)(col0 + bn) * K + bk;
  const ushort* blp = Btl + (size_t)(col0 + bn) * K + bk;

  for (int k0 = 0; k0 < K; k0 += 32) {
    float v[8];
    if (avalid) {
      float4 t0 = *(const float4*)(Arow + k0 + ak);
      float4 t1 = *(const float4*)(Arow + k0 + ak + 4);
      v[0] = t0.x; v[1] = t0.y; v[2] = t0.z; v[3] = t0.w;
      v[4] = t1.x; v[5] = t1.y; v[6] = t1.z; v[7] = t1.w;
    } else {
#pragma unroll
      for (int r = 0; r < 8; ++r) v[r] = 0.f;
    }
    s16x8 hv, lv;
#pragma unroll
    for (int r = 0; r < 8; ++r) {
      ushort h = f2bf(v[r]);
      hv[r] = (short)h;
      lv[r] = (short)f2bf(v[r] - bf2f(h));
    }
    *(s16x8*)&Ash[am][ak] = hv;
    *(s16x8*)&Asl[am][ak] = lv;
    *(s16x8*)&Bsh[bn][bk]     = *(const s16x8*)(bhp + k0);
    *(s16x8*)&Bsh[bn][bk + 8] = *(const s16x8*)(bhp + k0 + 8);
    *(s16x8*)&Bsl[bn][bk]     = *(const s16x8*)(blp + k0);
    *(s16x8*)&Bsl[bn][bk + 8] = *(const s16x8*)(blp + k0 + 8);
    __syncthreads();
    s16x8 ah[2], al[2], bh[4], bl[4];
#pragma unroll
    for (int i = 0; i < 2; ++i) {
      ah[i] = *(const s16x8*)&Ash[wm + i * 16 + fr][fq];
      al[i] = *(const s16x8*)&Asl[wm + i * 16 + fr][fq];
    }
#pragma unroll
    for (int j = 0; j < 4; ++j) {
      bh[j] = *(const s16x8*)&Bsh[wn + j * 16 + fr][fq];
      bl[j] = *(const s16x8*)&Bsl[wn + j * 16 + fr][fq];
    }
#pragma unroll
    for (int i = 0; i < 2; ++i)
#pragma unroll
      for (int j = 0; j < 4; ++j) {
        acc[i][j] = __builtin_amdgcn_mfma_f32_16x16x32_bf16(ah[i], bh[j], acc[i][j], 0, 0, 0);
        acc[i][j] = __builtin_amdgcn_mfma_f32_16x16x32_bf16(ah[i], bl[j], acc[i][j], 0, 0, 0);
        acc[i][j] = __builtin_amdgcn_mfma_f32_16x16x32_bf16(al[i], bh[j], acc[i][j], 0, 0, 0);
      }
    __syncthreads();
  }
  float asv[4], adv[4];
#pragma unroll
  for (int j = 0; j < 4; ++j) {
    asv[j] = a_s[hidx * 128 + wn + j * 16 + fr];
    adv[j] = a_d[hidx * 128 + wn + j * 16 + fr];
  }
  int rb = row0 + wm + ((lane >> 4) << 2);
  int cb = col0 + wn + fr;
#pragma unroll
  for (int i = 0; i < 2; ++i)
#pragma unroll
    for (int r = 0; r < 4; ++r) {
      int row = rb + i * 16 + r;
      float sp = 0.f, dp = 0.f;
#pragma unroll
      for (int j = 0; j < 4; ++j) {
        float c = acc[i][j][r];
        sp += c * asv[j];
        dp += c * adv[j];
        if (row < M) Cb[(size_t)row * N + cb + j * 16] = f2bf(c);
      }
#pragma unroll
      for (int m = 1; m < 16; m <<= 1) {
        sp += __shfl_xor(sp, m);
        dp += __shfl_xor(dp, m);
      }
      if ((lane & 15) == 0) {
        int rowb = wm + i * 16 + ((lane >> 4) << 2) + r;
        st_sh[0][rowb][wid >> 1] = sp;
        st_sh[1][rowb][wid >> 1] = dp;
      }
    }
  __syncthreads();
  if (tid < 64) {
    int row = row0 + tid;
    if (row < M) {
      asn[(size_t)row * H + hidx] = st_sh[0][tid][0] + st_sh[0][tid][1];
      adn[(size_t)row * H + hidx] = st_sh[1][tid][0] + st_sh[1][tid][1];
    }
  }
}

// ------- H=4 single-pass agg: wave/node, 8ch/lane, unnormalized + divide ----
__global__ __launch_bounds__(256) void agg4_kernel(
    const ushort* __restrict__ xl, const float* __restrict__ asn,
    const float* __restrict__ adn, const int* __restrict__ offsets,
    const int* __restrict__ srcs, const float* __restrict__ bias,
    float* __restrict__ out, int n) {
  __shared__ float alpha_sh[4][4][64];   // [wave][head][edge-in-chunk]
  __shared__ int src_sh[4][64];
  int wib = threadIdx.x >> 6, lane = threadIdx.x & 63;
  int nd = blockIdx.x * 4 + wib;
  if (nd >= n) return;
  int beg = offsets[nd], deg = offsets[nd + 1] - beg;
  float4 adl = *(const float4*)&adn[(size_t)nd * 4];
  int ch0 = lane << 3;                   // 8 channels/lane
  int hm = lane >> 4;                    // my head = ch0/128
  float den[4] = {0.f, 0.f, 0.f, 0.f};
  float acc[8] = {};

  for (int j0 = 0; j0 < deg; j0 += 64) {
    int j = j0 + lane;
    int s = 0;
    float w0 = 0.f, w1 = 0.f, w2 = 0.f, w3 = 0.f;
    if (j < deg) {
      s = srcs[beg + j];
      float4 av = *(const float4*)&asn[(size_t)s * 4];
      float e;
      e = av.x + adl.x; e = (e > 0.f) ? e : 0.2f * e; w0 = __expf(fminf(e, 30.f));
      e = av.y + adl.y; e = (e > 0.f) ? e : 0.2f * e; w1 = __expf(fminf(e, 30.f));
      e = av.z + adl.z; e = (e > 0.f) ? e : 0.2f * e; w2 = __expf(fminf(e, 30.f));
      e = av.w + adl.w; e = (e > 0.f) ? e : 0.2f * e; w3 = __expf(fminf(e, 30.f));
      den[0] += w0; den[1] += w1; den[2] += w2; den[3] += w3;
    }
    src_sh[wib][lane] = s;
    alpha_sh[wib][0][lane] = w0;
    alpha_sh[wib][1][lane] = w1;
    alpha_sh[wib][2][lane] = w2;
    alpha_sh[wib][3][lane] = w3;
    __builtin_amdgcn_wave_barrier();
    int cl = min(64, deg - j0);
    int jj = 0;
    for (; jj + 4 <= cl; jj += 4) {
      int4 sv = *(const int4*)&src_sh[wib][jj];
      float4 av = *(const float4*)&alpha_sh[wib][hm][jj];
      s16x8 v0 = *(const s16x8*)(xl + (size_t)sv.x * 512 + ch0);
      s16x8 v1 = *(const s16x8*)(xl + (size_t)sv.y * 512 + ch0);
      s16x8 v2 = *(const s16x8*)(xl + (size_t)sv.z * 512 + ch0);
      s16x8 v3 = *(const s16x8*)(xl + (size_t)sv.w * 512 + ch0);
#pragma unroll
      for (int i = 0; i < 8; ++i) acc[i] += av.x * bf2f((ushort)v0[i]);
#pragma unroll
      for (int i = 0; i < 8; ++i) acc[i] += av.y * bf2f((ushort)v1[i]);
#pragma unroll
      for (int i = 0; i < 8; ++i) acc[i] += av.z * bf2f((ushort)v2[i]);
#pragma unroll
      for (int i = 0; i < 8; ++i) acc[i] += av.w * bf2f((ushort)v3[i]);
    }
    for (; jj < cl; ++jj) {
      int s2 = src_sh[wib][jj];
      float a = alpha_sh[wib][hm][jj];
      s16x8 v = *(const s16x8*)(xl + (size_t)s2 * 512 + ch0);
#pragma unroll
      for (int i = 0; i < 8; ++i) acc[i] += a * bf2f((ushort)v[i]);
    }
    __builtin_amdgcn_wave_barrier();
  }
  // full-wave reduce of the 4 head denominators
#pragma unroll
  for (int h = 0; h < 4; ++h)
    for (int m = 1; m < 64; m <<= 1) den[h] += __shfl_xor(den[h], m);
  float d = (hm == 0) ? den[0] : (hm == 1) ? den[1] : (hm == 2) ? den[2] : den[3];
  float inv = 1.f / d;
  float* op = out + (size_t)nd * 512 + ch0;
#pragma unroll
  for (int i = 0; i < 8; ++i)
    op[i] = fmaxf(acc[i] * inv + bias[ch0 + i], 0.f);
}

// ------- H=1 single-pass agg (layer 2): wave/node, 2ch/lane, no relu -------
__global__ __launch_bounds__(256) void agg1_kernel(
    const ushort* __restrict__ xl, const float* __restrict__ asn,
    const float* __restrict__ adn, const int* __restrict__ offsets,
    const int* __restrict__ srcs, const float* __restrict__ bias,
    float* __restrict__ out, int n) {
  __shared__ float alpha_sh[4][64];
  __shared__ int src_sh[4][64];
  int wib = threadIdx.x >> 6, lane = threadIdx.x & 63;
  int nd = blockIdx.x * 4 + wib;
  if (nd >= n) return;
  int beg = offsets[nd], deg = offsets[nd + 1] - beg;
  float adl = adn[nd];
  int ch0 = lane << 1;
  float den = 0.f;
  float acc0 = 0.f, acc1 = 0.f;

  for (int j0 = 0; j0 < deg; j0 += 64) {
    int j = j0 + lane;
    int s = 0;
    float w = 0.f;
    if (j < deg) {
      s = srcs[beg + j];
      float e = asn[s] + adl;
      e = (e > 0.f) ? e : 0.2f * e;
      w = __expf(fminf(e, 30.f));
      den += w;
    }
    src_sh[wib][lane] = s;
    alpha_sh[wib][lane] = w;
    __builtin_amdgcn_wave_barrier();
    int cl = min(64, deg - j0);
    int jj = 0;
    for (; jj + 4 <= cl; jj += 4) {
      int4 sv = *(const int4*)&src_sh[wib][jj];
      float4 av = *(const float4*)&alpha_sh[wib][jj];
      uint v0 = *(const uint*)(xl + (size_t)sv.x * 128 + ch0);
      uint v1 = *(const uint*)(xl + (size_t)sv.y * 128 + ch0);
      uint v2 = *(const uint*)(xl + (size_t)sv.z * 128 + ch0);
      uint v3 = *(const uint*)(xl + (size_t)sv.w * 128 + ch0);
      acc0 += av.x * bf2f((ushort)(v0 & 0xFFFF));
      acc1 += av.x * bf2f((ushort)(v0 >> 16));
      acc0 += av.y * bf2f((ushort)(v1 & 0xFFFF));
      acc1 += av.y * bf2f((ushort)(v1 >> 16));
      acc0 += av.z * bf2f((ushort)(v2 & 0xFFFF));
      acc1 += av.z * bf2f((ushort)(v2 >> 16));
      acc0 += av.w * bf2f((ushort)(v3 & 0xFFFF));
      acc1 += av.w * bf2f((ushort)(v3 >> 16));
    }
    for (; jj < cl; ++jj) {
      int s2 = src_sh[wib][jj];
      float a = alpha_sh[wib][jj];
      uint v = *(const uint*)(xl + (size_t)s2 * 128 + ch0);
      acc0 += a * bf2f((ushort)(v & 0xFFFF));
      acc1 += a * bf2f((ushort)(v >> 16));
    }
    __builtin_amdgcn_wave_barrier();
  }
  for (int m = 1; m < 64; m <<= 1) den += __shfl_xor(den, m);
  float inv = 1.f / den;
  float* op = out + (size_t)nd * 128 + ch0;
  op[0] = acc0 * inv + bias[ch0 + 0];
  op[1] = acc1 * inv + bias[ch0 + 1];
}

// ---------------- mean pool (partial sums + atomics) ----------------
__global__ void pool_kernel(const float* __restrict__ h, float* __restrict__ g, int n) {
  int c = threadIdx.x;                 // 128 threads
  float acc = 0.f;
  for (int r = blockIdx.x; r < n; r += gridDim.x) acc += h[(size_t)r * 128 + c];
  atomicAdd(&g[c], acc);
}

// ---------------- final MLP ----------------
__global__ void mlp_kernel(const float* __restrict__ g, const float* __restrict__ Wm1,
                           const float* __restrict__ bm1, const float* __restrict__ Wm2,
                           const float* __restrict__ bm2, float* __restrict__ out,
                           float invn) {
  __shared__ float gs[128];
  __shared__ float hs[64];
  int t = threadIdx.x;                 // 64 threads
  gs[t] = g[t] * invn;
  gs[t + 64] = g[t + 64] * invn;
  __syncthreads();
  float acc = bm1[t];
  for (int c = 0; c < 128; ++c) acc += gs[c] * Wm1[c * 64 + t];
  hs[t] = fmaxf(acc, 0.f);
  __syncthreads();
  if (t == 0) {
    float o = bm2[0];
    for (int j = 0; j < 64; ++j) o += hs[j] * Wm2[j];
    out[0] = o;
  }
}

// ---------------------------------------------------------------------------
extern "C" void kernel_launch(void* const* d_in, const int* in_sizes, int n_in,
                              void* d_out, int out_size, void* d_ws, size_t ws_size,
                              hipStream_t stream) {
  const float* x   = (const float*)d_in[0];
  const int*   ei  = (const int*)d_in[1];
  const float* W0  = (const float*)d_in[2];
  const float* as0 = (const float*)d_in[3];
  const float* ad0 = (const float*)d_in[4];
  const float* b0  = (const float*)d_in[5];
  const float* W1  = (const float*)d_in[6];
  const float* as1 = (const float*)d_in[7];
  const float* ad1 = (const float*)d_in[8];
  const float* b1  = (const float*)d_in[9];
  const float* W2  = (const float*)d_in[10];
  const float* as2 = (const float*)d_in[11];
  const float* ad2 = (const float*)d_in[12];
  const float* b2  = (const float*)d_in[13];
  const float* Wm1 = (const float*)d_in[14];
  const float* bm1 = (const float*)d_in[15];
  const float* Wm2 = (const float*)d_in[16];
  const float* bm2 = (const float*)d_in[17];

  const int N = in_sizes[0] / 128;     // 20000
  const int E = in_sizes[1] / 2;       // 320000
  const int ET = E + N;                // with self loops

  // workspace layout
  float*  Bb  = (float*)d_ws;                     // N*512 fp32
  ushort* xlb = (ushort*)(Bb + (size_t)N * 512);  // N*512 bf16 xl
  float*  asn = (float*)(xlb + (size_t)N * 512);  // N*4
  float*  adn = asn + (size_t)N * 4;              // N*4
  float*  g   = adn + (size_t)N * 4;              // 128 pool accumulator
  int* counts = (int*)(g + 128);                  // N
  int* cursor = counts + N;                       // N
  int* offs   = cursor + N;                       // N+1
  int* srcs   = offs + N + 1;                     // ET
  int* parts  = srcs + ET;                        // 1024 scan partials
  ushort* w0h = (ushort*)(((uintptr_t)(parts + 1024) + 63) & ~(uintptr_t)63);
  ushort* w0l = w0h + 512 * 128;
  ushort* w1h = w0l + 512 * 128;
  ushort* w1l = w1h + 512 * 512;
  ushort* w2h = w1l + 512 * 512;
  ushort* w2l = w2h + 128 * 512;

  // zero pool accumulator + counts + cursor (contiguous)
  hipMemsetAsync(g, 0, (size_t)(128 + 2 * N) * sizeof(int), stream);

  wsplit_all_kernel<<<(98304 + 255) / 256, 256, 0, stream>>>(
      W0, W1, W2, w0h, w0l, w1h, w1l, w2h, w2l);

  // CSR by dst (multi-block scan)
  int ebl = (ET + 255) / 256;
  int nb = (N + 255) / 256;
  count_kernel<<<ebl, 256, 0, stream>>>(ei, counts, E, N);
  scan1_kernel<<<nb, 256, 0, stream>>>(counts, parts, N);
  scan2_kernel<<<1, 1024, 0, stream>>>(parts, nb);
  scan3_kernel<<<nb, 256, 0, stream>>>(counts, parts, offs, N);
  scatter_kernel<<<ebl, 256, 0, stream>>>(ei, offs, cursor, srcs, E, N);

  int nwb4 = (N + 3) / 4;              // 4 nodes/block
  dim3 gG01(4, (N + 63) / 64);
  dim3 gG2(1, (N + 63) / 64);

  // layer 0
  gemm_mfma_kernel<<<gG01, 256, 0, stream>>>(x, w0h, w0l, xlb, as0, ad0, asn, adn,
                                             N, 128, 512, 4);
  agg4_kernel<<<nwb4, 256, 0, stream>>>(xlb, asn, adn, offs, srcs, b0, Bb, N);

  // layer 1
  gemm_mfma_kernel<<<gG01, 256, 0, stream>>>(Bb, w1h, w1l, xlb, as1, ad1, asn, adn,
                                             N, 512, 512, 4);
  agg4_kernel<<<nwb4, 256, 0, stream>>>(xlb, asn, adn, offs, srcs, b1, Bb, N);

  // layer 2 (1 head, no relu)
  gemm_mfma_kernel<<<gG2, 256, 0, stream>>>(Bb, w2h, w2l, xlb, as2, ad2, asn, adn,
                                            N, 512, 128, 1);
  agg1_kernel<<<nwb4, 256, 0, stream>>>(xlb, asn, adn, offs, srcs, b2, Bb, N);

  // mean pool + MLP
  pool_kernel<<<128, 128, 0, stream>>>(Bb, g, N);
  mlp_kernel<<<1, 64, 0, stream>>>(g, Wm1, bm1, Wm2, bm2, (float*)d_out, 1.0f / (float)N);
}

// Round 9
// 381.849 us; speedup vs baseline: 1.2955x; 1.0164x over previous
//
#include <hip/hip_runtime.h>
#include <math.h>

// ---------------------------------------------------------------------------
// GAT pipeline (R9):
//   wsplit + CSR build  [once per launch]
//   per layer: split-bf16 MFMA GEMM (XCD-swizzled grid, quad-major LDS,
//              fused attn stats, bf16 xl out)
//              -> single-pass agg (unnormalized exp gather + divide)
//   mean pool -> 2-layer MLP -> scalar out
// R8 post-mortem: gemm top (53us K=512). FETCH 81MB vs 42 ideal (col-blocks
//   of one row-strip land on different XCDs -> per-XCD L2 refetch of A);
//   7.7M LDS bank conflicts from stride-20-word rows; Mfma 23%.
// R9: (a) 1D grid swizzle: id%8=row-residue, (id>>3)%NC=col -> row-strip's
//   col-blocks co-XCD (A strip fetched ~once/XCD); (b) LDS as s16x8[4][rows]
//   (quad-major): staging+fragment ops 16B/lane at uniform banks.
// ---------------------------------------------------------------------------

typedef float f32x4 __attribute__((ext_vector_type(4)));
typedef short s16x8 __attribute__((ext_vector_type(8)));
typedef short s16x4 __attribute__((ext_vector_type(4)));

__device__ inline ushort f2bf(float f) {
  unsigned u = __float_as_uint(f);
  u += 0x7FFF + ((u >> 16) & 1);          // round-to-nearest-even
  return (ushort)(u >> 16);
}
__device__ inline float bf2f(ushort h) { return __uint_as_float((unsigned)h << 16); }

// ---------------- CSR build ----------------
__global__ void count_kernel(const int* __restrict__ ei, int* __restrict__ counts,
                             int E, int n) {
  int t = blockIdx.x * blockDim.x + threadIdx.x;
  if (t < E) {
    atomicAdd(&counts[ei[E + t]], 1);          // dst row of edge_index
  } else if (t < E + n) {
    atomicAdd(&counts[t - E], 1);              // self loop
  }
}

__global__ void scan1_kernel(const int* __restrict__ counts, int* __restrict__ partials,
                             int n) {
  __shared__ int sd[4];
  int i = blockIdx.x * 256 + threadIdx.x;
  int v = (i < n) ? counts[i] : 0;
  for (int m = 32; m; m >>= 1) v += __shfl_xor(v, m);
  if ((threadIdx.x & 63) == 0) sd[threadIdx.x >> 6] = v;
  __syncthreads();
  if (threadIdx.x == 0) partials[blockIdx.x] = sd[0] + sd[1] + sd[2] + sd[3];
}

__global__ void scan2_kernel(int* __restrict__ partials, int nb) {
  __shared__ int sd[1024];
  int t = threadIdx.x;
  int v = (t < nb) ? partials[t] : 0;
  sd[t] = v;
  __syncthreads();
  for (int off = 1; off < 1024; off <<= 1) {
    int u = (t >= off) ? sd[t - off] : 0;
    __syncthreads();
    sd[t] += u;
    __syncthreads();
  }
  if (t < nb) partials[t] = sd[t] - v;
}

__global__ void scan3_kernel(const int* __restrict__ counts, const int* __restrict__ partials,
                             int* __restrict__ offsets, int n) {
  __shared__ int sd[256];
  int i = blockIdx.x * 256 + threadIdx.x;
  int t = threadIdx.x;
  int v = (i < n) ? counts[i] : 0;
  sd[t] = v;
  __syncthreads();
  for (int off = 1; off < 256; off <<= 1) {
    int u = (t >= off) ? sd[t - off] : 0;
    __syncthreads();
    sd[t] += u;
    __syncthreads();
  }
  int carry = partials[blockIdx.x];
  if (i < n) {
    offsets[i] = carry + sd[t] - v;
    if (i == n - 1) offsets[n] = carry + sd[t];
  }
}

__global__ void scatter_kernel(const int* __restrict__ ei, const int* __restrict__ offsets,
                               int* __restrict__ cursor, int* __restrict__ srcs,
                               int E, int n) {
  int t = blockIdx.x * blockDim.x + threadIdx.x;
  int s, d;
  if (t < E)          { s = ei[t]; d = ei[E + t]; }
  else if (t < E + n) { s = t - E; d = s; }
  else return;
  int pos = offsets[d] + atomicAdd(&cursor[d], 1);
  srcs[pos] = s;
}

// ------- weight transpose + bf16 split for all 3 layers in one launch -------
__global__ void wsplit_all_kernel(
    const float* __restrict__ W0, const float* __restrict__ W1,
    const float* __restrict__ W2, ushort* __restrict__ w0h, ushort* __restrict__ w0l,
    ushort* __restrict__ w1h, ushort* __restrict__ w1l, ushort* __restrict__ w2h,
    ushort* __restrict__ w2l) {
  int idx = blockIdx.x * 256 + threadIdx.x;
  const float* W; ushort *th, *tl; int K, N;
  if (idx < 16384)      { W = W0; th = w0h; tl = w0l; K = 128; N = 512; }
  else if (idx < 81920) { idx -= 16384; W = W1; th = w1h; tl = w1l; K = 512; N = 512; }
  else if (idx < 98304) { idx -= 81920; W = W2; th = w2h; tl = w2l; K = 512; N = 128; }
  else return;
  int n = idx % N;
  int k4 = (idx / N) << 2;
  s16x4 hv, lv;
#pragma unroll
  for (int r = 0; r < 4; ++r) {
    float w = W[(size_t)(k4 + r) * N + n];
    ushort h = f2bf(w);
    hv[r] = (short)h;
    lv[r] = (short)f2bf(w - bf2f(h));
  }
  *(s16x4*)&th[(size_t)n * K + k4] = hv;
  *(s16x4*)&tl[(size_t)n * K + k4] = lv;
}

// ---------------- split-bf16 MFMA GEMM + fused per-head attn stats ----------
// NC = number of 128-col blocks (4 or 1). Grid 1D, size rsp*NC (rsp = row
// strips padded to x8). id%8 = row residue -> col-blocks of a strip co-XCD.
// LDS quad-major: s16x8[quad][row] -> all ds ops 16B/lane, uniform banks.
template <int NC>
__global__ __launch_bounds__(256, 2) void gemm_mfma_kernel(
    const float* __restrict__ A, const ushort* __restrict__ Bth,
    const ushort* __restrict__ Btl, ushort* __restrict__ Cb,
    const float* __restrict__ a_s, const float* __restrict__ a_d,
    float* __restrict__ asn, float* __restrict__ adn,
    int M, int K) {
  constexpr int N = NC * 128;
  constexpr int H = NC;
  __shared__ s16x8 Ash[4][64], Asl[4][64];
  __shared__ s16x8 Bsh[4][128], Bsl[4][128];
  __shared__ float st_sh[2][64][2];
  int id = blockIdx.x;
  int rs = (id / (8 * NC)) * 8 + (id & 7);
  int row0 = rs * 64;
  if (row0 >= M) return;
  int hidx = (id >> 3) % NC;
  int col0 = hidx * 128;
  int tid = threadIdx.x;
  int am = tid >> 2, aq = tid & 3;            // A stage: row am, quad aq
  int bn = tid >> 1, bq = (tid & 1) << 1;     // B stage: row bn, quads bq,bq+1
  int lane = tid & 63, wid = tid >> 6;
  int wm = (wid & 1) << 5, wn = (wid >> 1) << 6;
  int fr = lane & 15, fqq = lane >> 4;        // fragment row, k-quad
  f32x4 acc[2][4] = {};
  const float* Arow = A + (size_t)(row0 + am) * K + aq * 8;
  bool avalid = (row0 + am) < M;
  const ushort* bhp = Bth + (size_t)(col0 + bn) * K + bq * 8;
  const ushort* blp = Btl + (size_t)(col0 + bn) * K + bq * 8;

  for (int k0 = 0; k0 < K; k0 += 32) {
    // ---- stage A (fp32 -> hi/lo bf16), 16B contiguous per lane ----
    float v[8];
    if (avalid) {
      float4 t0 = *(const float4*)(Arow + k0);
      float4 t1 = *(const float4*)(Arow + k0 + 4);
      v[0] = t0.x; v[1] = t0.y; v[2] = t0.z; v[3] = t0.w;
      v[4] = t1.x; v[5] = t1.y; v[6] = t1.z; v[7] = t1.w;
    } else {
#pragma unroll
      for (int r = 0; r < 8; ++r) v[r] = 0.f;
    }
    s16x8 hv, lv;
#pragma unroll
    for (int r = 0; r < 8; ++r) {
      ushort h = f2bf(v[r]);
      hv[r] = (short)h;
      lv[r] = (short)f2bf(v[r] - bf2f(h));
    }
    Ash[aq][am] = hv;
    Asl[aq][am] = lv;
    // ---- stage B (pre-split ushort copy) ----
    Bsh[bq][bn]     = *(const s16x8*)(bhp + k0);
    Bsh[bq + 1][bn] = *(const s16x8*)(bhp + k0 + 8);
    Bsl[bq][bn]     = *(const s16x8*)(blp + k0);
    Bsl[bq + 1][bn] = *(const s16x8*)(blp + k0 + 8);
    __syncthreads();
    // ---- fragments + MFMA (ah*bh + ah*bl + al*bh) ----
    s16x8 ah[2], al[2], bh[4], bl[4];
#pragma unroll
    for (int i = 0; i < 2; ++i) {
      ah[i] = Ash[fqq][wm + i * 16 + fr];
      al[i] = Asl[fqq][wm + i * 16 + fr];
    }
#pragma unroll
    for (int j = 0; j < 4; ++j) {
      bh[j] = Bsh[fqq][wn + j * 16 + fr];
      bl[j] = Bsl[fqq][wn + j * 16 + fr];
    }
#pragma unroll
    for (int i = 0; i < 2; ++i)
#pragma unroll
      for (int j = 0; j < 4; ++j) {
        acc[i][j] = __builtin_amdgcn_mfma_f32_16x16x32_bf16(ah[i], bh[j], acc[i][j], 0, 0, 0);
        acc[i][j] = __builtin_amdgcn_mfma_f32_16x16x32_bf16(ah[i], bl[j], acc[i][j], 0, 0, 0);
        acc[i][j] = __builtin_amdgcn_mfma_f32_16x16x32_bf16(al[i], bh[j], acc[i][j], 0, 0, 0);
      }
    __syncthreads();
  }
  // ---- epilogue: bf16 store + fused stats (from pre-rounding fp32) ----
  float asv[4], adv[4];
#pragma unroll
  for (int j = 0; j < 4; ++j) {
    asv[j] = a_s[hidx * 128 + wn + j * 16 + fr];
    adv[j] = a_d[hidx * 128 + wn + j * 16 + fr];
  }
  int rb = row0 + wm + ((lane >> 4) << 2);
  int cb = col0 + wn + fr;
#pragma unroll
  for (int i = 0; i < 2; ++i)
#pragma unroll
    for (int r = 0; r < 4; ++r) {
      int row = rb + i * 16 + r;
      float sp = 0.f, dp = 0.f;
#pragma unroll
      for (int j = 0; j < 4; ++j) {
        float c = acc[i][j][r];
        sp += c * asv[j];
        dp += c * adv[j];
        if (row < M) Cb[(size_t)row * N + cb + j * 16] = f2bf(c);
      }
#pragma unroll
      for (int m = 1; m < 16; m <<= 1) {
        sp += __shfl_xor(sp, m);
        dp += __shfl_xor(dp, m);
      }
      if ((lane & 15) == 0) {
        int rowb = wm + i * 16 + ((lane >> 4) << 2) + r;
        st_sh[0][rowb][wid >> 1] = sp;
        st_sh[1][rowb][wid >> 1] = dp;
      }
    }
  __syncthreads();
  if (tid < 64) {
    int row = row0 + tid;
    if (row < M) {
      asn[(size_t)row * H + hidx] = st_sh[0][tid][0] + st_sh[0][tid][1];
      adn[(size_t)row * H + hidx] = st_sh[1][tid][0] + st_sh[1][tid][1];
    }
  }
}

// ------- H=4 single-pass agg: wave/node, 8ch/lane, unnormalized + divide ----
__global__ __launch_bounds__(256) void agg4_kernel(
    const ushort* __restrict__ xl, const float* __restrict__ asn,
    const float* __restrict__ adn, const int* __restrict__ offsets,
    const int* __restrict__ srcs, const float* __restrict__ bias,
    float* __restrict__ out, int n) {
  __shared__ float alpha_sh[4][4][64];   // [wave][head][edge-in-chunk]
  __shared__ int src_sh[4][64];
  int wib = threadIdx.x >> 6, lane = threadIdx.x & 63;
  int nd = blockIdx.x * 4 + wib;
  if (nd >= n) return;
  int beg = offsets[nd], deg = offsets[nd + 1] - beg;
  float4 adl = *(const float4*)&adn[(size_t)nd * 4];
  int ch0 = lane << 3;                   // 8 channels/lane
  int hm = lane >> 4;                    // my head = ch0/128
  float den[4] = {0.f, 0.f, 0.f, 0.f};
  float acc[8] = {};

  for (int j0 = 0; j0 < deg; j0 += 64) {
    int j = j0 + lane;
    int s = 0;
    float w0 = 0.f, w1 = 0.f, w2 = 0.f, w3 = 0.f;
    if (j < deg) {
      s = srcs[beg + j];
      float4 av = *(const float4*)&asn[(size_t)s * 4];
      float e;
      e = av.x + adl.x; e = (e > 0.f) ? e : 0.2f * e; w0 = __expf(fminf(e, 30.f));
      e = av.y + adl.y; e = (e > 0.f) ? e : 0.2f * e; w1 = __expf(fminf(e, 30.f));
      e = av.z + adl.z; e = (e > 0.f) ? e : 0.2f * e; w2 = __expf(fminf(e, 30.f));
      e = av.w + adl.w; e = (e > 0.f) ? e : 0.2f * e; w3 = __expf(fminf(e, 30.f));
      den[0] += w0; den[1] += w1; den[2] += w2; den[3] += w3;
    }
    src_sh[wib][lane] = s;
    alpha_sh[wib][0][lane] = w0;
    alpha_sh[wib][1][lane] = w1;
    alpha_sh[wib][2][lane] = w2;
    alpha_sh[wib][3][lane] = w3;
    __builtin_amdgcn_wave_barrier();
    int cl = min(64, deg - j0);
    int jj = 0;
    for (; jj + 4 <= cl; jj += 4) {
      int4 sv = *(const int4*)&src_sh[wib][jj];
      float4 av = *(const float4*)&alpha_sh[wib][hm][jj];
      s16x8 v0 = *(const s16x8*)(xl + (size_t)sv.x * 512 + ch0);
      s16x8 v1 = *(const s16x8*)(xl + (size_t)sv.y * 512 + ch0);
      s16x8 v2 = *(const s16x8*)(xl + (size_t)sv.z * 512 + ch0);
      s16x8 v3 = *(const s16x8*)(xl + (size_t)sv.w * 512 + ch0);
#pragma unroll
      for (int i = 0; i < 8; ++i) acc[i] += av.x * bf2f((ushort)v0[i]);
#pragma unroll
      for (int i = 0; i < 8; ++i) acc[i] += av.y * bf2f((ushort)v1[i]);
#pragma unroll
      for (int i = 0; i < 8; ++i) acc[i] += av.z * bf2f((ushort)v2[i]);
#pragma unroll
      for (int i = 0; i < 8; ++i) acc[i] += av.w * bf2f((ushort)v3[i]);
    }
    for (; jj < cl; ++jj) {
      int s2 = src_sh[wib][jj];
      float a = alpha_sh[wib][hm][jj];
      s16x8 v = *(const s16x8*)(xl + (size_t)s2 * 512 + ch0);
#pragma unroll
      for (int i = 0; i < 8; ++i) acc[i] += a * bf2f((ushort)v[i]);
    }
    __builtin_amdgcn_wave_barrier();
  }
  // full-wave reduce of the 4 head denominators
#pragma unroll
  for (int h = 0; h < 4; ++h)
    for (int m = 1; m < 64; m <<= 1) den[h] += __shfl_xor(den[h], m);
  float d = (hm == 0) ? den[0] : (hm == 1) ? den[1] : (hm == 2) ? den[2] : den[3];
  float inv = 1.f / d;
  float* op = out + (size_t)nd * 512 + ch0;
#pragma unroll
  for (int i = 0; i < 8; ++i)
    op[i] = fmaxf(acc[i] * inv + bias[ch0 + i], 0.f);
}

// ------- H=1 single-pass agg (layer 2): wave/node, 2ch/lane, no relu -------
__global__ __launch_bounds__(256) void agg1_kernel(
    const ushort* __restrict__ xl, const float* __restrict__ asn,
    const float* __restrict__ adn, const int* __restrict__ offsets,
    const int* __restrict__ srcs, const float* __restrict__ bias,
    float* __restrict__ out, int n) {
  __shared__ float alpha_sh[4][64];
  __shared__ int src_sh[4][64];
  int wib = threadIdx.x >> 6, lane = threadIdx.x & 63;
  int nd = blockIdx.x * 4 + wib;
  if (nd >= n) return;
  int beg = offsets[nd], deg = offsets[nd + 1] - beg;
  float adl = adn[nd];
  int ch0 = lane << 1;
  float den = 0.f;
  float acc0 = 0.f, acc1 = 0.f;

  for (int j0 = 0; j0 < deg; j0 += 64) {
    int j = j0 + lane;
    int s = 0;
    float w = 0.f;
    if (j < deg) {
      s = srcs[beg + j];
      float e = asn[s] + adl;
      e = (e > 0.f) ? e : 0.2f * e;
      w = __expf(fminf(e, 30.f));
      den += w;
    }
    src_sh[wib][lane] = s;
    alpha_sh[wib][lane] = w;
    __builtin_amdgcn_wave_barrier();
    int cl = min(64, deg - j0);
    int jj = 0;
    for (; jj + 4 <= cl; jj += 4) {
      int4 sv = *(const int4*)&src_sh[wib][jj];
      float4 av = *(const float4*)&alpha_sh[wib][jj];
      uint v0 = *(const uint*)(xl + (size_t)sv.x * 128 + ch0);
      uint v1 = *(const uint*)(xl + (size_t)sv.y * 128 + ch0);
      uint v2 = *(const uint*)(xl + (size_t)sv.z * 128 + ch0);
      uint v3 = *(const uint*)(xl + (size_t)sv.w * 128 + ch0);
      acc0 += av.x * bf2f((ushort)(v0 & 0xFFFF));
      acc1 += av.x * bf2f((ushort)(v0 >> 16));
      acc0 += av.y * bf2f((ushort)(v1 & 0xFFFF));
      acc1 += av.y * bf2f((ushort)(v1 >> 16));
      acc0 += av.z * bf2f((ushort)(v2 & 0xFFFF));
      acc1 += av.z * bf2f((ushort)(v2 >> 16));
      acc0 += av.w * bf2f((ushort)(v3 & 0xFFFF));
      acc1 += av.w * bf2f((ushort)(v3 >> 16));
    }
    for (; jj < cl; ++jj) {
      int s2 = src_sh[wib][jj];
      float a = alpha_sh[wib][jj];
      uint v = *(const uint*)(xl + (size_t)s2 * 128 + ch0);
      acc0 += a * bf2f((ushort)(v & 0xFFFF));
      acc1 += a * bf2f((ushort)(v >> 16));
    }
    __builtin_amdgcn_wave_barrier();
  }
  for (int m = 1; m < 64; m <<= 1) den += __shfl_xor(den, m);
  float inv = 1.f / den;
  float* op = out + (size_t)nd * 128 + ch0;
  op[0] = acc0 * inv + bias[ch0 + 0];
  op[1] = acc1 * inv + bias[ch0 + 1];
}

// ---------------- mean pool (partial sums + atomics) ----------------
__global__ void pool_kernel(const float* __restrict__ h, float* __restrict__ g, int n) {
  int c = threadIdx.x;                 // 128 threads
  float acc = 0.f;
  for (int r = blockIdx.x; r < n; r += gridDim.x) acc += h[(size_t)r * 128 + c];
  atomicAdd(&g[c], acc);
}

// ---------------- final MLP ----------------
__global__ void mlp_kernel(const float* __restrict__ g, const float* __restrict__ Wm1,
                           const float* __restrict__ bm1, const float* __restrict__ Wm2,
                           const float* __restrict__ bm2, float* __restrict__ out,
                           float invn) {
  __shared__ float gs[128];
  __shared__ float hs[64];
  int t = threadIdx.x;                 // 64 threads
  gs[t] = g[t] * invn;
  gs[t + 64] = g[t + 64] * invn;
  __syncthreads();
  float acc = bm1[t];
  for (int c = 0; c < 128; ++c) acc += gs[c] * Wm1[c * 64 + t];
  hs[t] = fmaxf(acc, 0.f);
  __syncthreads();
  if (t == 0) {
    float o = bm2[0];
    for (int j = 0; j < 64; ++j) o += hs[j] * Wm2[j];
    out[0] = o;
  }
}

// ---------------------------------------------------------------------------
extern "C" void kernel_launch(void* const* d_in, const int* in_sizes, int n_in,
                              void* d_out, int out_size, void* d_ws, size_t ws_size,
                              hipStream_t stream) {
  const float* x   = (const float*)d_in[0];
  const int*   ei  = (const int*)d_in[1];
  const float* W0  = (const float*)d_in[2];
  const float* as0 = (const float*)d_in[3];
  const float* ad0 = (const float*)d_in[4];
  const float* b0  = (const float*)d_in[5];
  const float* W1  = (const float*)d_in[6];
  const float* as1 = (const float*)d_in[7];
  const float* ad1 = (const float*)d_in[8];
  const float* b1  = (const float*)d_in[9];
  const float* W2  = (const float*)d_in[10];
  const float* as2 = (const float*)d_in[11];
  const float* ad2 = (const float*)d_in[12];
  const float* b2  = (const float*)d_in[13];
  const float* Wm1 = (const float*)d_in[14];
  const float* bm1 = (const float*)d_in[15];
  const float* Wm2 = (const float*)d_in[16];
  const float* bm2 = (const float*)d_in[17];

  const int N = in_sizes[0] / 128;     // 20000
  const int E = in_sizes[1] / 2;       // 320000
  const int ET = E + N;                // with self loops

  // workspace layout
  float*  Bb  = (float*)d_ws;                     // N*512 fp32
  ushort* xlb = (ushort*)(Bb + (size_t)N * 512);  // N*512 bf16 xl
  float*  asn = (float*)(xlb + (size_t)N * 512);  // N*4
  float*  adn = asn + (size_t)N * 4;              // N*4
  float*  g   = adn + (size_t)N * 4;              // 128 pool accumulator
  int* counts = (int*)(g + 128);                  // N
  int* cursor = counts + N;                       // N
  int* offs   = cursor + N;                       // N+1
  int* srcs   = offs + N + 1;                     // ET
  int* parts  = srcs + ET;                        // 1024 scan partials
  ushort* w0h = (ushort*)(((uintptr_t)(parts + 1024) + 63) & ~(uintptr_t)63);
  ushort* w0l = w0h + 512 * 128;
  ushort* w1h = w0l + 512 * 128;
  ushort* w1l = w1h + 512 * 512;
  ushort* w2h = w1l + 512 * 512;
  ushort* w2l = w2h + 128 * 512;

  // zero pool accumulator + counts + cursor (contiguous)
  hipMemsetAsync(g, 0, (size_t)(128 + 2 * N) * sizeof(int), stream);

  wsplit_all_kernel<<<(98304 + 255) / 256, 256, 0, stream>>>(
      W0, W1, W2, w0h, w0l, w1h, w1l, w2h, w2l);

  // CSR by dst (multi-block scan)
  int ebl = (ET + 255) / 256;
  int nb = (N + 255) / 256;
  count_kernel<<<ebl, 256, 0, stream>>>(ei, counts, E, N);
  scan1_kernel<<<nb, 256, 0, stream>>>(counts, parts, N);
  scan2_kernel<<<1, 1024, 0, stream>>>(parts, nb);
  scan3_kernel<<<nb, 256, 0, stream>>>(counts, parts, offs, N);
  scatter_kernel<<<ebl, 256, 0, stream>>>(ei, offs, cursor, srcs, E, N);

  int nwb4 = (N + 3) / 4;              // 4 nodes/block
  int rsn = (N + 63) / 64;             // 313 row strips
  int rsp = ((rsn + 7) / 8) * 8;       // 320 (pad to x8 for swizzle)
  int blk01 = rsp * 4;                 // 1280 blocks (NC=4)
  int blk2 = rsp;                      // 320 blocks (NC=1)

  // layer 0
  gemm_mfma_kernel<4><<<blk01, 256, 0, stream>>>(x, w0h, w0l, xlb, as0, ad0,
                                                 asn, adn, N, 128);
  agg4_kernel<<<nwb4, 256, 0, stream>>>(xlb, asn, adn, offs, srcs, b0, Bb, N);

  // layer 1
  gemm_mfma_kernel<4><<<blk01, 256, 0, stream>>>(Bb, w1h, w1l, xlb, as1, ad1,
                                                 asn, adn, N, 512);
  agg4_kernel<<<nwb4, 256, 0, stream>>>(xlb, asn, adn, offs, srcs, b1, Bb, N);

  // layer 2 (1 head, no relu)
  gemm_mfma_kernel<1><<<blk2, 256, 0, stream>>>(Bb, w2h, w2l, xlb, as2, ad2,
                                                asn, adn, N, 512);
  agg1_kernel<<<nwb4, 256, 0, stream>>>(xlb, asn, adn, offs, srcs, b2, Bb, N);

  // mean pool + MLP
  pool_kernel<<<128, 128, 0, stream>>>(Bb, g, N);
  mlp_kernel<<<1, 64, 0, stream>>>(g, Wm1, bm1, Wm2, bm2, (float*)d_out, 1.0f / (float)N);
}

// Round 10
// 369.145 us; speedup vs baseline: 1.3401x; 1.0344x over previous
//
#include <hip/hip_runtime.h>
#include <math.h>

// ---------------------------------------------------------------------------
// GAT pipeline (R10):
//   wsplit + CSR build  [once per launch]
//   L0: fp32-A split-bf16 MFMA GEMM (3 mfma) -> xl bf16 + stats
//   L1/2: bf16-A GEMM (2 mfma: ah*bh+ah*bl, weights split = exact)
//   agg4: single-pass exp gather, batch-8, bf16 output h
//   agg1 -> h2 fp32; mean pool -> MLP
// R9 post-mortem: gemm off top-5 (swizzle+quad-LDS worked). agg4 top at
//   50.7us, 148MB @ 3.8TB/s, VALU 30% -> BW-efficiency-bound.
// R10 rationale: node-local errors average in mean pool (/sqrt(20000));
//   weight errors are correlated -> keep weights split-exact, store h bf16.
//   2/3 MFMA + half A-traffic on L1/L2 GEMMs; half agg writes; batch-8
//   gather (52 VGPR, still 8 waves/SIMD).
// ---------------------------------------------------------------------------

typedef float f32x4 __attribute__((ext_vector_type(4)));
typedef short s16x8 __attribute__((ext_vector_type(8)));
typedef short s16x4 __attribute__((ext_vector_type(4)));

__device__ inline ushort f2bf(float f) {
  unsigned u = __float_as_uint(f);
  u += 0x7FFF + ((u >> 16) & 1);          // round-to-nearest-even
  return (ushort)(u >> 16);
}
__device__ inline float bf2f(ushort h) { return __uint_as_float((unsigned)h << 16); }

// ---------------- CSR build ----------------
__global__ void count_kernel(const int* __restrict__ ei, int* __restrict__ counts,
                             int E, int n) {
  int t = blockIdx.x * blockDim.x + threadIdx.x;
  if (t < E) {
    atomicAdd(&counts[ei[E + t]], 1);          // dst row of edge_index
  } else if (t < E + n) {
    atomicAdd(&counts[t - E], 1);              // self loop
  }
}

__global__ void scan1_kernel(const int* __restrict__ counts, int* __restrict__ partials,
                             int n) {
  __shared__ int sd[4];
  int i = blockIdx.x * 256 + threadIdx.x;
  int v = (i < n) ? counts[i] : 0;
  for (int m = 32; m; m >>= 1) v += __shfl_xor(v, m);
  if ((threadIdx.x & 63) == 0) sd[threadIdx.x >> 6] = v;
  __syncthreads();
  if (threadIdx.x == 0) partials[blockIdx.x] = sd[0] + sd[1] + sd[2] + sd[3];
}

__global__ void scan2_kernel(int* __restrict__ partials, int nb) {
  __shared__ int sd[1024];
  int t = threadIdx.x;
  int v = (t < nb) ? partials[t] : 0;
  sd[t] = v;
  __syncthreads();
  for (int off = 1; off < 1024; off <<= 1) {
    int u = (t >= off) ? sd[t - off] : 0;
    __syncthreads();
    sd[t] += u;
    __syncthreads();
  }
  if (t < nb) partials[t] = sd[t] - v;
}

__global__ void scan3_kernel(const int* __restrict__ counts, const int* __restrict__ partials,
                             int* __restrict__ offsets, int n) {
  __shared__ int sd[256];
  int i = blockIdx.x * 256 + threadIdx.x;
  int t = threadIdx.x;
  int v = (i < n) ? counts[i] : 0;
  sd[t] = v;
  __syncthreads();
  for (int off = 1; off < 256; off <<= 1) {
    int u = (t >= off) ? sd[t - off] : 0;
    __syncthreads();
    sd[t] += u;
    __syncthreads();
  }
  int carry = partials[blockIdx.x];
  if (i < n) {
    offsets[i] = carry + sd[t] - v;
    if (i == n - 1) offsets[n] = carry + sd[t];
  }
}

__global__ void scatter_kernel(const int* __restrict__ ei, const int* __restrict__ offsets,
                               int* __restrict__ cursor, int* __restrict__ srcs,
                               int E, int n) {
  int t = blockIdx.x * blockDim.x + threadIdx.x;
  int s, d;
  if (t < E)          { s = ei[t]; d = ei[E + t]; }
  else if (t < E + n) { s = t - E; d = s; }
  else return;
  int pos = offsets[d] + atomicAdd(&cursor[d], 1);
  srcs[pos] = s;
}

// ------- weight transpose + bf16 split for all 3 layers in one launch -------
__global__ void wsplit_all_kernel(
    const float* __restrict__ W0, const float* __restrict__ W1,
    const float* __restrict__ W2, ushort* __restrict__ w0h, ushort* __restrict__ w0l,
    ushort* __restrict__ w1h, ushort* __restrict__ w1l, ushort* __restrict__ w2h,
    ushort* __restrict__ w2l) {
  int idx = blockIdx.x * 256 + threadIdx.x;
  const float* W; ushort *th, *tl; int K, N;
  if (idx < 16384)      { W = W0; th = w0h; tl = w0l; K = 128; N = 512; }
  else if (idx < 81920) { idx -= 16384; W = W1; th = w1h; tl = w1l; K = 512; N = 512; }
  else if (idx < 98304) { idx -= 81920; W = W2; th = w2h; tl = w2l; K = 512; N = 128; }
  else return;
  int n = idx % N;
  int k4 = (idx / N) << 2;
  s16x4 hv, lv;
#pragma unroll
  for (int r = 0; r < 4; ++r) {
    float w = W[(size_t)(k4 + r) * N + n];
    ushort h = f2bf(w);
    hv[r] = (short)h;
    lv[r] = (short)f2bf(w - bf2f(h));
  }
  *(s16x4*)&th[(size_t)n * K + k4] = hv;
  *(s16x4*)&tl[(size_t)n * K + k4] = lv;
}

// ---------------- shared GEMM epilogue (bf16 store + fused stats) ----------
template <int NC>
__device__ inline void gemm_epilogue(
    f32x4 (&acc)[2][4], ushort* __restrict__ Cb, const float* __restrict__ a_s,
    const float* __restrict__ a_d, float* __restrict__ asn, float* __restrict__ adn,
    float (*st_sh)[64][2], int M, int row0, int col0, int hidx,
    int tid, int lane, int wid, int wm, int wn, int fr) {
  constexpr int N = NC * 128;
  float asv[4], adv[4];
#pragma unroll
  for (int j = 0; j < 4; ++j) {
    asv[j] = a_s[hidx * 128 + wn + j * 16 + fr];
    adv[j] = a_d[hidx * 128 + wn + j * 16 + fr];
  }
  int rb = row0 + wm + ((lane >> 4) << 2);
  int cb = col0 + wn + fr;
#pragma unroll
  for (int i = 0; i < 2; ++i)
#pragma unroll
    for (int r = 0; r < 4; ++r) {
      int row = rb + i * 16 + r;
      float sp = 0.f, dp = 0.f;
#pragma unroll
      for (int j = 0; j < 4; ++j) {
        float c = acc[i][j][r];
        sp += c * asv[j];
        dp += c * adv[j];
        if (row < M) Cb[(size_t)row * N + cb + j * 16] = f2bf(c);
      }
#pragma unroll
      for (int m = 1; m < 16; m <<= 1) {
        sp += __shfl_xor(sp, m);
        dp += __shfl_xor(dp, m);
      }
      if ((lane & 15) == 0) {
        int rowb = wm + i * 16 + ((lane >> 4) << 2) + r;
        st_sh[0][rowb][wid >> 1] = sp;
        st_sh[1][rowb][wid >> 1] = dp;
      }
    }
  __syncthreads();
  if (tid < 64) {
    int row = row0 + tid;
    if (row < M) {
      asn[(size_t)row * NC + hidx] = st_sh[0][tid][0] + st_sh[0][tid][1];
      adn[(size_t)row * NC + hidx] = st_sh[1][tid][0] + st_sh[1][tid][1];
    }
  }
}

// -------- fp32-A split GEMM (layer 0): 3 MFMA (ah*bh+ah*bl+al*bh) ---------
template <int NC>
__global__ __launch_bounds__(256, 2) void gemm_f32a_kernel(
    const float* __restrict__ A, const ushort* __restrict__ Bth,
    const ushort* __restrict__ Btl, ushort* __restrict__ Cb,
    const float* __restrict__ a_s, const float* __restrict__ a_d,
    float* __restrict__ asn, float* __restrict__ adn,
    int M, int K) {
  __shared__ s16x8 Ash[4][64], Asl[4][64];
  __shared__ s16x8 Bsh[4][128], Bsl[4][128];
  __shared__ float st_sh[2][64][2];
  int id = blockIdx.x;
  int rs = (id / (8 * NC)) * 8 + (id & 7);
  int row0 = rs * 64;
  if (row0 >= M) return;
  int hidx = (id >> 3) % NC;
  int col0 = hidx * 128;
  int tid = threadIdx.x;
  int am = tid >> 2, aq = tid & 3;
  int bn = tid >> 1, bq = (tid & 1) << 1;
  int lane = tid & 63, wid = tid >> 6;
  int wm = (wid & 1) << 5, wn = (wid >> 1) << 6;
  int fr = lane & 15, fqq = lane >> 4;
  f32x4 acc[2][4] = {};
  const float* Arow = A + (size_t)(row0 + am) * K + aq * 8;
  bool avalid = (row0 + am) < M;
  const ushort* bhp = Bth + (size_t)(col0 + bn) * K + bq * 8;
  const ushort* blp = Btl + (size_t)(col0 + bn) * K + bq * 8;

  for (int k0 = 0; k0 < K; k0 += 32) {
    float v[8];
    if (avalid) {
      float4 t0 = *(const float4*)(Arow + k0);
      float4 t1 = *(const float4*)(Arow + k0 + 4);
      v[0] = t0.x; v[1] = t0.y; v[2] = t0.z; v[3] = t0.w;
      v[4] = t1.x; v[5] = t1.y; v[6] = t1.z; v[7] = t1.w;
    } else {
#pragma unroll
      for (int r = 0; r < 8; ++r) v[r] = 0.f;
    }
    s16x8 hv, lv;
#pragma unroll
    for (int r = 0; r < 8; ++r) {
      ushort h = f2bf(v[r]);
      hv[r] = (short)h;
      lv[r] = (short)f2bf(v[r] - bf2f(h));
    }
    Ash[aq][am] = hv;
    Asl[aq][am] = lv;
    Bsh[bq][bn]     = *(const s16x8*)(bhp + k0);
    Bsh[bq + 1][bn] = *(const s16x8*)(bhp + k0 + 8);
    Bsl[bq][bn]     = *(const s16x8*)(blp + k0);
    Bsl[bq + 1][bn] = *(const s16x8*)(blp + k0 + 8);
    __syncthreads();
    s16x8 ah[2], al[2], bh[4], bl[4];
#pragma unroll
    for (int i = 0; i < 2; ++i) {
      ah[i] = Ash[fqq][wm + i * 16 + fr];
      al[i] = Asl[fqq][wm + i * 16 + fr];
    }
#pragma unroll
    for (int j = 0; j < 4; ++j) {
      bh[j] = Bsh[fqq][wn + j * 16 + fr];
      bl[j] = Bsl[fqq][wn + j * 16 + fr];
    }
#pragma unroll
    for (int i = 0; i < 2; ++i)
#pragma unroll
      for (int j = 0; j < 4; ++j) {
        acc[i][j] = __builtin_amdgcn_mfma_f32_16x16x32_bf16(ah[i], bh[j], acc[i][j], 0, 0, 0);
        acc[i][j] = __builtin_amdgcn_mfma_f32_16x16x32_bf16(ah[i], bl[j], acc[i][j], 0, 0, 0);
        acc[i][j] = __builtin_amdgcn_mfma_f32_16x16x32_bf16(al[i], bh[j], acc[i][j], 0, 0, 0);
      }
    __syncthreads();
  }
  gemm_epilogue<NC>(acc, Cb, a_s, a_d, asn, adn, st_sh, M, row0, col0, hidx,
                    tid, lane, wid, wm, wn, fr);
}

// -------- bf16-A GEMM (layers 1,2): 2 MFMA (ah*bh + ah*bl) ---------------
template <int NC>
__global__ __launch_bounds__(256, 2) void gemm_bf16a_kernel(
    const ushort* __restrict__ A, const ushort* __restrict__ Bth,
    const ushort* __restrict__ Btl, ushort* __restrict__ Cb,
    const float* __restrict__ a_s, const float* __restrict__ a_d,
    float* __restrict__ asn, float* __restrict__ adn,
    int M, int K) {
  __shared__ s16x8 Ash[4][64];
  __shared__ s16x8 Bsh[4][128], Bsl[4][128];
  __shared__ float st_sh[2][64][2];
  int id = blockIdx.x;
  int rs = (id / (8 * NC)) * 8 + (id & 7);
  int row0 = rs * 64;
  if (row0 >= M) return;
  int hidx = (id >> 3) % NC;
  int col0 = hidx * 128;
  int tid = threadIdx.x;
  int am = tid >> 2, aq = tid & 3;
  int bn = tid >> 1, bq = (tid & 1) << 1;
  int lane = tid & 63, wid = tid >> 6;
  int wm = (wid & 1) << 5, wn = (wid >> 1) << 6;
  int fr = lane & 15, fqq = lane >> 4;
  f32x4 acc[2][4] = {};
  const ushort* Arow = A + (size_t)(row0 + am) * K + aq * 8;
  bool avalid = (row0 + am) < M;
  const ushort* bhp = Bth + (size_t)(col0 + bn) * K + bq * 8;
  const ushort* blp = Btl + (size_t)(col0 + bn) * K + bq * 8;
  const s16x8 zero8 = {};

  for (int k0 = 0; k0 < K; k0 += 32) {
    Ash[aq][am] = avalid ? *(const s16x8*)(Arow + k0) : zero8;
    Bsh[bq][bn]     = *(const s16x8*)(bhp + k0);
    Bsh[bq + 1][bn] = *(const s16x8*)(bhp + k0 + 8);
    Bsl[bq][bn]     = *(const s16x8*)(blp + k0);
    Bsl[bq + 1][bn] = *(const s16x8*)(blp + k0 + 8);
    __syncthreads();
    s16x8 ah[2], bh[4], bl[4];
#pragma unroll
    for (int i = 0; i < 2; ++i) ah[i] = Ash[fqq][wm + i * 16 + fr];
#pragma unroll
    for (int j = 0; j < 4; ++j) {
      bh[j] = Bsh[fqq][wn + j * 16 + fr];
      bl[j] = Bsl[fqq][wn + j * 16 + fr];
    }
#pragma unroll
    for (int i = 0; i < 2; ++i)
#pragma unroll
      for (int j = 0; j < 4; ++j) {
        acc[i][j] = __builtin_amdgcn_mfma_f32_16x16x32_bf16(ah[i], bh[j], acc[i][j], 0, 0, 0);
        acc[i][j] = __builtin_amdgcn_mfma_f32_16x16x32_bf16(ah[i], bl[j], acc[i][j], 0, 0, 0);
      }
    __syncthreads();
  }
  gemm_epilogue<NC>(acc, Cb, a_s, a_d, asn, adn, st_sh, M, row0, col0, hidx,
                    tid, lane, wid, wm, wn, fr);
}

// ------- H=4 single-pass agg: wave/node, 8ch/lane, batch-8, bf16 out -------
__global__ __launch_bounds__(256) void agg4_kernel(
    const ushort* __restrict__ xl, const float* __restrict__ asn,
    const float* __restrict__ adn, const int* __restrict__ offsets,
    const int* __restrict__ srcs, const float* __restrict__ bias,
    ushort* __restrict__ out, int n) {
  __shared__ float alpha_sh[4][4][64];   // [wave][head][edge-in-chunk]
  __shared__ int src_sh[4][64];
  int wib = threadIdx.x >> 6, lane = threadIdx.x & 63;
  int nd = blockIdx.x * 4 + wib;
  if (nd >= n) return;
  int beg = offsets[nd], deg = offsets[nd + 1] - beg;
  float4 adl = *(const float4*)&adn[(size_t)nd * 4];
  int ch0 = lane << 3;                   // 8 channels/lane
  int hm = lane >> 4;                    // my head = ch0/128
  float den[4] = {0.f, 0.f, 0.f, 0.f};
  float acc[8] = {};

  for (int j0 = 0; j0 < deg; j0 += 64) {
    int j = j0 + lane;
    int s = 0;
    float w0 = 0.f, w1 = 0.f, w2 = 0.f, w3 = 0.f;
    if (j < deg) {
      s = srcs[beg + j];
      float4 av = *(const float4*)&asn[(size_t)s * 4];
      float e;
      e = av.x + adl.x; e = (e > 0.f) ? e : 0.2f * e; w0 = __expf(fminf(e, 30.f));
      e = av.y + adl.y; e = (e > 0.f) ? e : 0.2f * e; w1 = __expf(fminf(e, 30.f));
      e = av.z + adl.z; e = (e > 0.f) ? e : 0.2f * e; w2 = __expf(fminf(e, 30.f));
      e = av.w + adl.w; e = (e > 0.f) ? e : 0.2f * e; w3 = __expf(fminf(e, 30.f));
      den[0] += w0; den[1] += w1; den[2] += w2; den[3] += w3;
    }
    src_sh[wib][lane] = s;
    alpha_sh[wib][0][lane] = w0;
    alpha_sh[wib][1][lane] = w1;
    alpha_sh[wib][2][lane] = w2;
    alpha_sh[wib][3][lane] = w3;
    __builtin_amdgcn_wave_barrier();
    int cl = min(64, deg - j0);
    int jj = 0;
    for (; jj + 8 <= cl; jj += 8) {
      int4 sv0 = *(const int4*)&src_sh[wib][jj];
      int4 sv1 = *(const int4*)&src_sh[wib][jj + 4];
      float4 av0 = *(const float4*)&alpha_sh[wib][hm][jj];
      float4 av1 = *(const float4*)&alpha_sh[wib][hm][jj + 4];
      s16x8 v0 = *(const s16x8*)(xl + (size_t)sv0.x * 512 + ch0);
      s16x8 v1 = *(const s16x8*)(xl + (size_t)sv0.y * 512 + ch0);
      s16x8 v2 = *(const s16x8*)(xl + (size_t)sv0.z * 512 + ch0);
      s16x8 v3 = *(const s16x8*)(xl + (size_t)sv0.w * 512 + ch0);
      s16x8 v4 = *(const s16x8*)(xl + (size_t)sv1.x * 512 + ch0);
      s16x8 v5 = *(const s16x8*)(xl + (size_t)sv1.y * 512 + ch0);
      s16x8 v6 = *(const s16x8*)(xl + (size_t)sv1.z * 512 + ch0);
      s16x8 v7 = *(const s16x8*)(xl + (size_t)sv1.w * 512 + ch0);
#pragma unroll
      for (int i = 0; i < 8; ++i) acc[i] += av0.x * bf2f((ushort)v0[i]);
#pragma unroll
      for (int i = 0; i < 8; ++i) acc[i] += av0.y * bf2f((ushort)v1[i]);
#pragma unroll
      for (int i = 0; i < 8; ++i) acc[i] += av0.z * bf2f((ushort)v2[i]);
#pragma unroll
      for (int i = 0; i < 8; ++i) acc[i] += av0.w * bf2f((ushort)v3[i]);
#pragma unroll
      for (int i = 0; i < 8; ++i) acc[i] += av1.x * bf2f((ushort)v4[i]);
#pragma unroll
      for (int i = 0; i < 8; ++i) acc[i] += av1.y * bf2f((ushort)v5[i]);
#pragma unroll
      for (int i = 0; i < 8; ++i) acc[i] += av1.z * bf2f((ushort)v6[i]);
#pragma unroll
      for (int i = 0; i < 8; ++i) acc[i] += av1.w * bf2f((ushort)v7[i]);
    }
    for (; jj < cl; ++jj) {
      int s2 = src_sh[wib][jj];
      float a = alpha_sh[wib][hm][jj];
      s16x8 v = *(const s16x8*)(xl + (size_t)s2 * 512 + ch0);
#pragma unroll
      for (int i = 0; i < 8; ++i) acc[i] += a * bf2f((ushort)v[i]);
    }
    __builtin_amdgcn_wave_barrier();
  }
  // full-wave reduce of the 4 head denominators
#pragma unroll
  for (int h = 0; h < 4; ++h)
    for (int m = 1; m < 64; m <<= 1) den[h] += __shfl_xor(den[h], m);
  float d = (hm == 0) ? den[0] : (hm == 1) ? den[1] : (hm == 2) ? den[2] : den[3];
  float inv = 1.f / d;
  s16x8 ob;
#pragma unroll
  for (int i = 0; i < 8; ++i)
    ob[i] = (short)f2bf(fmaxf(acc[i] * inv + bias[ch0 + i], 0.f));
  *(s16x8*)(out + (size_t)nd * 512 + ch0) = ob;
}

// ------- H=1 single-pass agg (layer 2): wave/node, 2ch/lane, fp32 out ------
__global__ __launch_bounds__(256) void agg1_kernel(
    const ushort* __restrict__ xl, const float* __restrict__ asn,
    const float* __restrict__ adn, const int* __restrict__ offsets,
    const int* __restrict__ srcs, const float* __restrict__ bias,
    float* __restrict__ out, int n) {
  __shared__ float alpha_sh[4][64];
  __shared__ int src_sh[4][64];
  int wib = threadIdx.x >> 6, lane = threadIdx.x & 63;
  int nd = blockIdx.x * 4 + wib;
  if (nd >= n) return;
  int beg = offsets[nd], deg = offsets[nd + 1] - beg;
  float adl = adn[nd];
  int ch0 = lane << 1;
  float den = 0.f;
  float acc0 = 0.f, acc1 = 0.f;

  for (int j0 = 0; j0 < deg; j0 += 64) {
    int j = j0 + lane;
    int s = 0;
    float w = 0.f;
    if (j < deg) {
      s = srcs[beg + j];
      float e = asn[s] + adl;
      e = (e > 0.f) ? e : 0.2f * e;
      w = __expf(fminf(e, 30.f));
      den += w;
    }
    src_sh[wib][lane] = s;
    alpha_sh[wib][lane] = w;
    __builtin_amdgcn_wave_barrier();
    int cl = min(64, deg - j0);
    int jj = 0;
    for (; jj + 4 <= cl; jj += 4) {
      int4 sv = *(const int4*)&src_sh[wib][jj];
      float4 av = *(const float4*)&alpha_sh[wib][jj];
      uint v0 = *(const uint*)(xl + (size_t)sv.x * 128 + ch0);
      uint v1 = *(const uint*)(xl + (size_t)sv.y * 128 + ch0);
      uint v2 = *(const uint*)(xl + (size_t)sv.z * 128 + ch0);
      uint v3 = *(const uint*)(xl + (size_t)sv.w * 128 + ch0);
      acc0 += av.x * bf2f((ushort)(v0 & 0xFFFF));
      acc1 += av.x * bf2f((ushort)(v0 >> 16));
      acc0 += av.y * bf2f((ushort)(v1 & 0xFFFF));
      acc1 += av.y * bf2f((ushort)(v1 >> 16));
      acc0 += av.z * bf2f((ushort)(v2 & 0xFFFF));
      acc1 += av.z * bf2f((ushort)(v2 >> 16));
      acc0 += av.w * bf2f((ushort)(v3 & 0xFFFF));
      acc1 += av.w * bf2f((ushort)(v3 >> 16));
    }
    for (; jj < cl; ++jj) {
      int s2 = src_sh[wib][jj];
      float a = alpha_sh[wib][jj];
      uint v = *(const uint*)(xl + (size_t)s2 * 128 + ch0);
      acc0 += a * bf2f((ushort)(v & 0xFFFF));
      acc1 += a * bf2f((ushort)(v >> 16));
    }
    __builtin_amdgcn_wave_barrier();
  }
  for (int m = 1; m < 64; m <<= 1) den += __shfl_xor(den, m);
  float inv = 1.f / den;
  float* op = out + (size_t)nd * 128 + ch0;
  op[0] = acc0 * inv + bias[ch0 + 0];
  op[1] = acc1 * inv + bias[ch0 + 1];
}

// ---------------- mean pool (partial sums + atomics) ----------------
__global__ void pool_kernel(const float* __restrict__ h, float* __restrict__ g, int n) {
  int c = threadIdx.x;                 // 128 threads
  float acc = 0.f;
  for (int r = blockIdx.x; r < n; r += gridDim.x) acc += h[(size_t)r * 128 + c];
  atomicAdd(&g[c], acc);
}

// ---------------- final MLP ----------------
__global__ void mlp_kernel(const float* __restrict__ g, const float* __restrict__ Wm1,
                           const float* __restrict__ bm1, const float* __restrict__ Wm2,
                           const float* __restrict__ bm2, float* __restrict__ out,
                           float invn) {
  __shared__ float gs[128];
  __shared__ float hs[64];
  int t = threadIdx.x;                 // 64 threads
  gs[t] = g[t] * invn;
  gs[t + 64] = g[t + 64] * invn;
  __syncthreads();
  float acc = bm1[t];
  for (int c = 0; c < 128; ++c) acc += gs[c] * Wm1[c * 64 + t];
  hs[t] = fmaxf(acc, 0.f);
  __syncthreads();
  if (t == 0) {
    float o = bm2[0];
    for (int j = 0; j < 64; ++j) o += hs[j] * Wm2[j];
    out[0] = o;
  }
}

// ---------------------------------------------------------------------------
extern "C" void kernel_launch(void* const* d_in, const int* in_sizes, int n_in,
                              void* d_out, int out_size, void* d_ws, size_t ws_size,
                              hipStream_t stream) {
  const float* x   = (const float*)d_in[0];
  const int*   ei  = (const int*)d_in[1];
  const float* W0  = (const float*)d_in[2];
  const float* as0 = (const float*)d_in[3];
  const float* ad0 = (const float*)d_in[4];
  const float* b0  = (const float*)d_in[5];
  const float* W1  = (const float*)d_in[6];
  const float* as1 = (const float*)d_in[7];
  const float* ad1 = (const float*)d_in[8];
  const float* b1  = (const float*)d_in[9];
  const float* W2  = (const float*)d_in[10];
  const float* as2 = (const float*)d_in[11];
  const float* ad2 = (const float*)d_in[12];
  const float* b2  = (const float*)d_in[13];
  const float* Wm1 = (const float*)d_in[14];
  const float* bm1 = (const float*)d_in[15];
  const float* Wm2 = (const float*)d_in[16];
  const float* bm2 = (const float*)d_in[17];

  const int N = in_sizes[0] / 128;     // 20000
  const int E = in_sizes[1] / 2;       // 320000
  const int ET = E + N;                // with self loops

  // workspace layout
  ushort* hb  = (ushort*)d_ws;                    // N*512 bf16 (h between layers)
  ushort* xlb = hb + (size_t)N * 512;             // N*512 bf16 xl
  float*  h2  = (float*)(xlb + (size_t)N * 512);  // N*128 fp32 (pool input)
  float*  asn = h2 + (size_t)N * 128;             // N*4
  float*  adn = asn + (size_t)N * 4;              // N*4
  float*  g   = adn + (size_t)N * 4;              // 128 pool accumulator
  int* counts = (int*)(g + 128);                  // N
  int* cursor = counts + N;                       // N
  int* offs   = cursor + N;                       // N+1
  int* srcs   = offs + N + 1;                     // ET
  int* parts  = srcs + ET;                        // 1024 scan partials
  ushort* w0h = (ushort*)(((uintptr_t)(parts + 1024) + 63) & ~(uintptr_t)63);
  ushort* w0l = w0h + 512 * 128;
  ushort* w1h = w0l + 512 * 128;
  ushort* w1l = w1h + 512 * 512;
  ushort* w2h = w1l + 512 * 512;
  ushort* w2l = w2h + 128 * 512;

  // zero pool accumulator + counts + cursor (contiguous)
  hipMemsetAsync(g, 0, (size_t)(128 + 2 * N) * sizeof(int), stream);

  wsplit_all_kernel<<<(98304 + 255) / 256, 256, 0, stream>>>(
      W0, W1, W2, w0h, w0l, w1h, w1l, w2h, w2l);

  // CSR by dst (multi-block scan)
  int ebl = (ET + 255) / 256;
  int nb = (N + 255) / 256;
  count_kernel<<<ebl, 256, 0, stream>>>(ei, counts, E, N);
  scan1_kernel<<<nb, 256, 0, stream>>>(counts, parts, N);
  scan2_kernel<<<1, 1024, 0, stream>>>(parts, nb);
  scan3_kernel<<<nb, 256, 0, stream>>>(counts, parts, offs, N);
  scatter_kernel<<<ebl, 256, 0, stream>>>(ei, offs, cursor, srcs, E, N);

  int nwb4 = (N + 3) / 4;              // 4 nodes/block
  int rsn = (N + 63) / 64;             // 313 row strips
  int rsp = ((rsn + 7) / 8) * 8;       // 320 (pad to x8 for swizzle)
  int blk01 = rsp * 4;                 // NC=4
  int blk2 = rsp;                      // NC=1

  // layer 0: fp32 x -> xlb + stats
  gemm_f32a_kernel<4><<<blk01, 256, 0, stream>>>(x, w0h, w0l, xlb, as0, ad0,
                                                 asn, adn, N, 128);
  agg4_kernel<<<nwb4, 256, 0, stream>>>(xlb, asn, adn, offs, srcs, b0, hb, N);

  // layer 1: bf16 h0 -> xlb + stats
  gemm_bf16a_kernel<4><<<blk01, 256, 0, stream>>>(hb, w1h, w1l, xlb, as1, ad1,
                                                  asn, adn, N, 512);
  agg4_kernel<<<nwb4, 256, 0, stream>>>(xlb, asn, adn, offs, srcs, b1, hb, N);

  // layer 2: bf16 h1 -> xlb (N*128) + stats; agg1 -> h2 fp32
  gemm_bf16a_kernel<1><<<blk2, 256, 0, stream>>>(hb, w2h, w2l, xlb, as2, ad2,
                                                 asn, adn, N, 512);
  agg1_kernel<<<nwb4, 256, 0, stream>>>(xlb, asn, adn, offs, srcs, b2, h2, N);

  // mean pool + MLP
  pool_kernel<<<128, 128, 0, stream>>>(h2, g, N);
  mlp_kernel<<<1, 64, 0, stream>>>(g, Wm1, bm1, Wm2, bm2, (float*)d_out, 1.0f / (float)N);
}

// Round 11
// 333.431 us; speedup vs baseline: 1.4836x; 1.1071x over previous
//
#include <hip/hip_runtime.h>
#include <math.h>

// ---------------------------------------------------------------------------
// GAT pipeline (R11):
//   wsplit + CSR build  [once per launch]
//   L0: fp32-A split-bf16 MFMA GEMM (3 mfma) -> xl fp8 + exact stats
//   L1/2: bf16-A GEMM (2 mfma, weights hi+lo exact) -> xl fp8 + stats
//   agg4: single-pass exp gather over fp8 xl (batch-8), bf16 h out
//   agg1 -> h2 fp32; mean pool -> MLP
// R10 post-mortem: agg4 FETCH pinned at 148MB = 8 XCDs x ~18.5MB = compulsory
//   per-XCD stream of the 20MB bf16 xl table (private L2s, random mapping).
//   Byte reduction is the only lever left on this floor.
// R11: xl payload fp8 e4m3 via HW cvt_pk (round-trip consistent); stats stay
//   fp32-accum-exact, weights stay split-exact, h stays bf16. Node-local
//   ~2% rms quantization noise averages out in the 20000-node mean pool.
// ---------------------------------------------------------------------------

typedef float f32x4 __attribute__((ext_vector_type(4)));
typedef float f32x2 __attribute__((ext_vector_type(2)));
typedef short s16x8 __attribute__((ext_vector_type(8)));
typedef short s16x4 __attribute__((ext_vector_type(4)));

__device__ inline ushort f2bf(float f) {
  unsigned u = __float_as_uint(f);
  u += 0x7FFF + ((u >> 16) & 1);          // round-to-nearest-even
  return (ushort)(u >> 16);
}
__device__ inline float bf2f(ushort h) { return __uint_as_float((unsigned)h << 16); }
__device__ inline unsigned char f2fp8(float f) {
  int p = __builtin_amdgcn_cvt_pk_fp8_f32(f, f, 0, false);
  return (unsigned char)(p & 0xFF);
}

// ---------------- CSR build ----------------
__global__ void count_kernel(const int* __restrict__ ei, int* __restrict__ counts,
                             int E, int n) {
  int t = blockIdx.x * blockDim.x + threadIdx.x;
  if (t < E) {
    atomicAdd(&counts[ei[E + t]], 1);          // dst row of edge_index
  } else if (t < E + n) {
    atomicAdd(&counts[t - E], 1);              // self loop
  }
}

__global__ void scan1_kernel(const int* __restrict__ counts, int* __restrict__ partials,
                             int n) {
  __shared__ int sd[4];
  int i = blockIdx.x * 256 + threadIdx.x;
  int v = (i < n) ? counts[i] : 0;
  for (int m = 32; m; m >>= 1) v += __shfl_xor(v, m);
  if ((threadIdx.x & 63) == 0) sd[threadIdx.x >> 6] = v;
  __syncthreads();
  if (threadIdx.x == 0) partials[blockIdx.x] = sd[0] + sd[1] + sd[2] + sd[3];
}

__global__ void scan2_kernel(int* __restrict__ partials, int nb) {
  __shared__ int sd[1024];
  int t = threadIdx.x;
  int v = (t < nb) ? partials[t] : 0;
  sd[t] = v;
  __syncthreads();
  for (int off = 1; off < 1024; off <<= 1) {
    int u = (t >= off) ? sd[t - off] : 0;
    __syncthreads();
    sd[t] += u;
    __syncthreads();
  }
  if (t < nb) partials[t] = sd[t] - v;
}

__global__ void scan3_kernel(const int* __restrict__ counts, const int* __restrict__ partials,
                             int* __restrict__ offsets, int n) {
  __shared__ int sd[256];
  int i = blockIdx.x * 256 + threadIdx.x;
  int t = threadIdx.x;
  int v = (i < n) ? counts[i] : 0;
  sd[t] = v;
  __syncthreads();
  for (int off = 1; off < 256; off <<= 1) {
    int u = (t >= off) ? sd[t - off] : 0;
    __syncthreads();
    sd[t] += u;
    __syncthreads();
  }
  int carry = partials[blockIdx.x];
  if (i < n) {
    offsets[i] = carry + sd[t] - v;
    if (i == n - 1) offsets[n] = carry + sd[t];
  }
}

__global__ void scatter_kernel(const int* __restrict__ ei, const int* __restrict__ offsets,
                               int* __restrict__ cursor, int* __restrict__ srcs,
                               int E, int n) {
  int t = blockIdx.x * blockDim.x + threadIdx.x;
  int s, d;
  if (t < E)          { s = ei[t]; d = ei[E + t]; }
  else if (t < E + n) { s = t - E; d = s; }
  else return;
  int pos = offsets[d] + atomicAdd(&cursor[d], 1);
  srcs[pos] = s;
}

// ------- weight transpose + bf16 split for all 3 layers in one launch -------
__global__ void wsplit_all_kernel(
    const float* __restrict__ W0, const float* __restrict__ W1,
    const float* __restrict__ W2, ushort* __restrict__ w0h, ushort* __restrict__ w0l,
    ushort* __restrict__ w1h, ushort* __restrict__ w1l, ushort* __restrict__ w2h,
    ushort* __restrict__ w2l) {
  int idx = blockIdx.x * 256 + threadIdx.x;
  const float* W; ushort *th, *tl; int K, N;
  if (idx < 16384)      { W = W0; th = w0h; tl = w0l; K = 128; N = 512; }
  else if (idx < 81920) { idx -= 16384; W = W1; th = w1h; tl = w1l; K = 512; N = 512; }
  else if (idx < 98304) { idx -= 81920; W = W2; th = w2h; tl = w2l; K = 512; N = 128; }
  else return;
  int n = idx % N;
  int k4 = (idx / N) << 2;
  s16x4 hv, lv;
#pragma unroll
  for (int r = 0; r < 4; ++r) {
    float w = W[(size_t)(k4 + r) * N + n];
    ushort h = f2bf(w);
    hv[r] = (short)h;
    lv[r] = (short)f2bf(w - bf2f(h));
  }
  *(s16x4*)&th[(size_t)n * K + k4] = hv;
  *(s16x4*)&tl[(size_t)n * K + k4] = lv;
}

// ---------------- shared GEMM epilogue (fp8 store + fused stats) ----------
template <int NC>
__device__ inline void gemm_epilogue(
    f32x4 (&acc)[2][4], unsigned char* __restrict__ Cb, const float* __restrict__ a_s,
    const float* __restrict__ a_d, float* __restrict__ asn, float* __restrict__ adn,
    float (*st_sh)[64][2], int M, int row0, int col0, int hidx,
    int tid, int lane, int wid, int wm, int wn, int fr) {
  constexpr int N = NC * 128;
  float asv[4], adv[4];
#pragma unroll
  for (int j = 0; j < 4; ++j) {
    asv[j] = a_s[hidx * 128 + wn + j * 16 + fr];
    adv[j] = a_d[hidx * 128 + wn + j * 16 + fr];
  }
  int rb = row0 + wm + ((lane >> 4) << 2);
  int cb = col0 + wn + fr;
#pragma unroll
  for (int i = 0; i < 2; ++i)
#pragma unroll
    for (int r = 0; r < 4; ++r) {
      int row = rb + i * 16 + r;
      float sp = 0.f, dp = 0.f;
#pragma unroll
      for (int j = 0; j < 4; ++j) {
        float c = acc[i][j][r];
        sp += c * asv[j];
        dp += c * adv[j];
        if (row < M) Cb[(size_t)row * N + cb + j * 16] = f2fp8(c);
      }
#pragma unroll
      for (int m = 1; m < 16; m <<= 1) {
        sp += __shfl_xor(sp, m);
        dp += __shfl_xor(dp, m);
      }
      if ((lane & 15) == 0) {
        int rowb = wm + i * 16 + ((lane >> 4) << 2) + r;
        st_sh[0][rowb][wid >> 1] = sp;
        st_sh[1][rowb][wid >> 1] = dp;
      }
    }
  __syncthreads();
  if (tid < 64) {
    int row = row0 + tid;
    if (row < M) {
      asn[(size_t)row * NC + hidx] = st_sh[0][tid][0] + st_sh[0][tid][1];
      adn[(size_t)row * NC + hidx] = st_sh[1][tid][0] + st_sh[1][tid][1];
    }
  }
}

// -------- fp32-A split GEMM (layer 0): 3 MFMA (ah*bh+ah*bl+al*bh) ---------
template <int NC>
__global__ __launch_bounds__(256, 2) void gemm_f32a_kernel(
    const float* __restrict__ A, const ushort* __restrict__ Bth,
    const ushort* __restrict__ Btl, unsigned char* __restrict__ Cb,
    const float* __restrict__ a_s, const float* __restrict__ a_d,
    float* __restrict__ asn, float* __restrict__ adn,
    int M, int K) {
  __shared__ s16x8 Ash[4][64], Asl[4][64];
  __shared__ s16x8 Bsh[4][128], Bsl[4][128];
  __shared__ float st_sh[2][64][2];
  int id = blockIdx.x;
  int rs = (id / (8 * NC)) * 8 + (id & 7);
  int row0 = rs * 64;
  if (row0 >= M) return;
  int hidx = (id >> 3) % NC;
  int col0 = hidx * 128;
  int tid = threadIdx.x;
  int am = tid >> 2, aq = tid & 3;
  int bn = tid >> 1, bq = (tid & 1) << 1;
  int lane = tid & 63, wid = tid >> 6;
  int wm = (wid & 1) << 5, wn = (wid >> 1) << 6;
  int fr = lane & 15, fqq = lane >> 4;
  f32x4 acc[2][4] = {};
  const float* Arow = A + (size_t)(row0 + am) * K + aq * 8;
  bool avalid = (row0 + am) < M;
  const ushort* bhp = Bth + (size_t)(col0 + bn) * K + bq * 8;
  const ushort* blp = Btl + (size_t)(col0 + bn) * K + bq * 8;

  for (int k0 = 0; k0 < K; k0 += 32) {
    float v[8];
    if (avalid) {
      float4 t0 = *(const float4*)(Arow + k0);
      float4 t1 = *(const float4*)(Arow + k0 + 4);
      v[0] = t0.x; v[1] = t0.y; v[2] = t0.z; v[3] = t0.w;
      v[4] = t1.x; v[5] = t1.y; v[6] = t1.z; v[7] = t1.w;
    } else {
#pragma unroll
      for (int r = 0; r < 8; ++r) v[r] = 0.f;
    }
    s16x8 hv, lv;
#pragma unroll
    for (int r = 0; r < 8; ++r) {
      ushort h = f2bf(v[r]);
      hv[r] = (short)h;
      lv[r] = (short)f2bf(v[r] - bf2f(h));
    }
    Ash[aq][am] = hv;
    Asl[aq][am] = lv;
    Bsh[bq][bn]     = *(const s16x8*)(bhp + k0);
    Bsh[bq + 1][bn] = *(const s16x8*)(bhp + k0 + 8);
    Bsl[bq][bn]     = *(const s16x8*)(blp + k0);
    Bsl[bq + 1][bn] = *(const s16x8*)(blp + k0 + 8);
    __syncthreads();
    s16x8 ah[2], al[2], bh[4], bl[4];
#pragma unroll
    for (int i = 0; i < 2; ++i) {
      ah[i] = Ash[fqq][wm + i * 16 + fr];
      al[i] = Asl[fqq][wm + i * 16 + fr];
    }
#pragma unroll
    for (int j = 0; j < 4; ++j) {
      bh[j] = Bsh[fqq][wn + j * 16 + fr];
      bl[j] = Bsl[fqq][wn + j * 16 + fr];
    }
#pragma unroll
    for (int i = 0; i < 2; ++i)
#pragma unroll
      for (int j = 0; j < 4; ++j) {
        acc[i][j] = __builtin_amdgcn_mfma_f32_16x16x32_bf16(ah[i], bh[j], acc[i][j], 0, 0, 0);
        acc[i][j] = __builtin_amdgcn_mfma_f32_16x16x32_bf16(ah[i], bl[j], acc[i][j], 0, 0, 0);
        acc[i][j] = __builtin_amdgcn_mfma_f32_16x16x32_bf16(al[i], bh[j], acc[i][j], 0, 0, 0);
      }
    __syncthreads();
  }
  gemm_epilogue<NC>(acc, Cb, a_s, a_d, asn, adn, st_sh, M, row0, col0, hidx,
                    tid, lane, wid, wm, wn, fr);
}

// -------- bf16-A GEMM (layers 1,2): 2 MFMA (ah*bh + ah*bl) ---------------
template <int NC>
__global__ __launch_bounds__(256, 2) void gemm_bf16a_kernel(
    const ushort* __restrict__ A, const ushort* __restrict__ Bth,
    const ushort* __restrict__ Btl, unsigned char* __restrict__ Cb,
    const float* __restrict__ a_s, const float* __restrict__ a_d,
    float* __restrict__ asn, float* __restrict__ adn,
    int M, int K) {
  __shared__ s16x8 Ash[4][64];
  __shared__ s16x8 Bsh[4][128], Bsl[4][128];
  __shared__ float st_sh[2][64][2];
  int id = blockIdx.x;
  int rs = (id / (8 * NC)) * 8 + (id & 7);
  int row0 = rs * 64;
  if (row0 >= M) return;
  int hidx = (id >> 3) % NC;
  int col0 = hidx * 128;
  int tid = threadIdx.x;
  int am = tid >> 2, aq = tid & 3;
  int bn = tid >> 1, bq = (tid & 1) << 1;
  int lane = tid & 63, wid = tid >> 6;
  int wm = (wid & 1) << 5, wn = (wid >> 1) << 6;
  int fr = lane & 15, fqq = lane >> 4;
  f32x4 acc[2][4] = {};
  const ushort* Arow = A + (size_t)(row0 + am) * K + aq * 8;
  bool avalid = (row0 + am) < M;
  const ushort* bhp = Bth + (size_t)(col0 + bn) * K + bq * 8;
  const ushort* blp = Btl + (size_t)(col0 + bn) * K + bq * 8;
  const s16x8 zero8 = {};

  for (int k0 = 0; k0 < K; k0 += 32) {
    Ash[aq][am] = avalid ? *(const s16x8*)(Arow + k0) : zero8;
    Bsh[bq][bn]     = *(const s16x8*)(bhp + k0);
    Bsh[bq + 1][bn] = *(const s16x8*)(bhp + k0 + 8);
    Bsl[bq][bn]     = *(const s16x8*)(blp + k0);
    Bsl[bq + 1][bn] = *(const s16x8*)(blp + k0 + 8);
    __syncthreads();
    s16x8 ah[2], bh[4], bl[4];
#pragma unroll
    for (int i = 0; i < 2; ++i) ah[i] = Ash[fqq][wm + i * 16 + fr];
#pragma unroll
    for (int j = 0; j < 4; ++j) {
      bh[j] = Bsh[fqq][wn + j * 16 + fr];
      bl[j] = Bsl[fqq][wn + j * 16 + fr];
    }
#pragma unroll
    for (int i = 0; i < 2; ++i)
#pragma unroll
      for (int j = 0; j < 4; ++j) {
        acc[i][j] = __builtin_amdgcn_mfma_f32_16x16x32_bf16(ah[i], bh[j], acc[i][j], 0, 0, 0);
        acc[i][j] = __builtin_amdgcn_mfma_f32_16x16x32_bf16(ah[i], bl[j], acc[i][j], 0, 0, 0);
      }
    __syncthreads();
  }
  gemm_epilogue<NC>(acc, Cb, a_s, a_d, asn, adn, st_sh, M, row0, col0, hidx,
                    tid, lane, wid, wm, wn, fr);
}

// ------- H=4 single-pass agg: wave/node, 8ch/lane, batch-8 fp8, bf16 out ---
__global__ __launch_bounds__(256) void agg4_kernel(
    const unsigned char* __restrict__ xl, const float* __restrict__ asn,
    const float* __restrict__ adn, const int* __restrict__ offsets,
    const int* __restrict__ srcs, const float* __restrict__ bias,
    ushort* __restrict__ out, int n) {
  __shared__ float alpha_sh[4][4][64];   // [wave][head][edge-in-chunk]
  __shared__ int src_sh[4][64];
  int wib = threadIdx.x >> 6, lane = threadIdx.x & 63;
  int nd = blockIdx.x * 4 + wib;
  if (nd >= n) return;
  int beg = offsets[nd], deg = offsets[nd + 1] - beg;
  float4 adl = *(const float4*)&adn[(size_t)nd * 4];
  int ch0 = lane << 3;                   // 8 channels/lane (bytes in fp8)
  int hm = lane >> 4;                    // my head = ch0/128
  float den[4] = {0.f, 0.f, 0.f, 0.f};
  float acc[8] = {};

  for (int j0 = 0; j0 < deg; j0 += 64) {
    int j = j0 + lane;
    int s = 0;
    float w0 = 0.f, w1 = 0.f, w2 = 0.f, w3 = 0.f;
    if (j < deg) {
      s = srcs[beg + j];
      float4 av = *(const float4*)&asn[(size_t)s * 4];
      float e;
      e = av.x + adl.x; e = (e > 0.f) ? e : 0.2f * e; w0 = __expf(fminf(e, 30.f));
      e = av.y + adl.y; e = (e > 0.f) ? e : 0.2f * e; w1 = __expf(fminf(e, 30.f));
      e = av.z + adl.z; e = (e > 0.f) ? e : 0.2f * e; w2 = __expf(fminf(e, 30.f));
      e = av.w + adl.w; e = (e > 0.f) ? e : 0.2f * e; w3 = __expf(fminf(e, 30.f));
      den[0] += w0; den[1] += w1; den[2] += w2; den[3] += w3;
    }
    src_sh[wib][lane] = s;
    alpha_sh[wib][0][lane] = w0;
    alpha_sh[wib][1][lane] = w1;
    alpha_sh[wib][2][lane] = w2;
    alpha_sh[wib][3][lane] = w3;
    __builtin_amdgcn_wave_barrier();
    int cl = min(64, deg - j0);
    int jj = 0;
    for (; jj + 8 <= cl; jj += 8) {
      int4 sv0 = *(const int4*)&src_sh[wib][jj];
      int4 sv1 = *(const int4*)&src_sh[wib][jj + 4];
      float4 av0 = *(const float4*)&alpha_sh[wib][hm][jj];
      float4 av1 = *(const float4*)&alpha_sh[wib][hm][jj + 4];
      uint2 v[8];
      v[0] = *(const uint2*)(xl + (size_t)sv0.x * 512 + ch0);
      v[1] = *(const uint2*)(xl + (size_t)sv0.y * 512 + ch0);
      v[2] = *(const uint2*)(xl + (size_t)sv0.z * 512 + ch0);
      v[3] = *(const uint2*)(xl + (size_t)sv0.w * 512 + ch0);
      v[4] = *(const uint2*)(xl + (size_t)sv1.x * 512 + ch0);
      v[5] = *(const uint2*)(xl + (size_t)sv1.y * 512 + ch0);
      v[6] = *(const uint2*)(xl + (size_t)sv1.z * 512 + ch0);
      v[7] = *(const uint2*)(xl + (size_t)sv1.w * 512 + ch0);
      float a[8] = {av0.x, av0.y, av0.z, av0.w, av1.x, av1.y, av1.z, av1.w};
#pragma unroll
      for (int u = 0; u < 8; ++u) {
        f32x2 c01 = __builtin_amdgcn_cvt_pk_f32_fp8((int)v[u].x, false);
        f32x2 c23 = __builtin_amdgcn_cvt_pk_f32_fp8((int)v[u].x, true);
        f32x2 c45 = __builtin_amdgcn_cvt_pk_f32_fp8((int)v[u].y, false);
        f32x2 c67 = __builtin_amdgcn_cvt_pk_f32_fp8((int)v[u].y, true);
        acc[0] += a[u] * c01[0]; acc[1] += a[u] * c01[1];
        acc[2] += a[u] * c23[0]; acc[3] += a[u] * c23[1];
        acc[4] += a[u] * c45[0]; acc[5] += a[u] * c45[1];
        acc[6] += a[u] * c67[0]; acc[7] += a[u] * c67[1];
      }
    }
    for (; jj < cl; ++jj) {
      int s2 = src_sh[wib][jj];
      float a = alpha_sh[wib][hm][jj];
      uint2 v = *(const uint2*)(xl + (size_t)s2 * 512 + ch0);
      f32x2 c01 = __builtin_amdgcn_cvt_pk_f32_fp8((int)v.x, false);
      f32x2 c23 = __builtin_amdgcn_cvt_pk_f32_fp8((int)v.x, true);
      f32x2 c45 = __builtin_amdgcn_cvt_pk_f32_fp8((int)v.y, false);
      f32x2 c67 = __builtin_amdgcn_cvt_pk_f32_fp8((int)v.y, true);
      acc[0] += a * c01[0]; acc[1] += a * c01[1];
      acc[2] += a * c23[0]; acc[3] += a * c23[1];
      acc[4] += a * c45[0]; acc[5] += a * c45[1];
      acc[6] += a * c67[0]; acc[7] += a * c67[1];
    }
    __builtin_amdgcn_wave_barrier();
  }
  // full-wave reduce of the 4 head denominators
#pragma unroll
  for (int h = 0; h < 4; ++h)
    for (int m = 1; m < 64; m <<= 1) den[h] += __shfl_xor(den[h], m);
  float d = (hm == 0) ? den[0] : (hm == 1) ? den[1] : (hm == 2) ? den[2] : den[3];
  float inv = 1.f / d;
  s16x8 ob;
#pragma unroll
  for (int i = 0; i < 8; ++i)
    ob[i] = (short)f2bf(fmaxf(acc[i] * inv + bias[ch0 + i], 0.f));
  *(s16x8*)(out + (size_t)nd * 512 + ch0) = ob;
}

// ------- H=1 single-pass agg (layer 2): wave/node, 2ch/lane fp8, fp32 out --
__global__ __launch_bounds__(256) void agg1_kernel(
    const unsigned char* __restrict__ xl, const float* __restrict__ asn,
    const float* __restrict__ adn, const int* __restrict__ offsets,
    const int* __restrict__ srcs, const float* __restrict__ bias,
    float* __restrict__ out, int n) {
  __shared__ float alpha_sh[4][64];
  __shared__ int src_sh[4][64];
  int wib = threadIdx.x >> 6, lane = threadIdx.x & 63;
  int nd = blockIdx.x * 4 + wib;
  if (nd >= n) return;
  int beg = offsets[nd], deg = offsets[nd + 1] - beg;
  float adl = adn[nd];
  int ch0 = lane << 1;
  float den = 0.f;
  float acc0 = 0.f, acc1 = 0.f;

  for (int j0 = 0; j0 < deg; j0 += 64) {
    int j = j0 + lane;
    int s = 0;
    float w = 0.f;
    if (j < deg) {
      s = srcs[beg + j];
      float e = asn[s] + adl;
      e = (e > 0.f) ? e : 0.2f * e;
      w = __expf(fminf(e, 30.f));
      den += w;
    }
    src_sh[wib][lane] = s;
    alpha_sh[wib][lane] = w;
    __builtin_amdgcn_wave_barrier();
    int cl = min(64, deg - j0);
    int jj = 0;
    for (; jj + 4 <= cl; jj += 4) {
      int4 sv = *(const int4*)&src_sh[wib][jj];
      float4 av = *(const float4*)&alpha_sh[wib][jj];
      uint v0 = *(const ushort*)(xl + (size_t)sv.x * 128 + ch0);
      uint v1 = *(const ushort*)(xl + (size_t)sv.y * 128 + ch0);
      uint v2 = *(const ushort*)(xl + (size_t)sv.z * 128 + ch0);
      uint v3 = *(const ushort*)(xl + (size_t)sv.w * 128 + ch0);
      f32x2 c0 = __builtin_amdgcn_cvt_pk_f32_fp8((int)v0, false);
      f32x2 c1 = __builtin_amdgcn_cvt_pk_f32_fp8((int)v1, false);
      f32x2 c2 = __builtin_amdgcn_cvt_pk_f32_fp8((int)v2, false);
      f32x2 c3 = __builtin_amdgcn_cvt_pk_f32_fp8((int)v3, false);
      acc0 += av.x * c0[0]; acc1 += av.x * c0[1];
      acc0 += av.y * c1[0]; acc1 += av.y * c1[1];
      acc0 += av.z * c2[0]; acc1 += av.z * c2[1];
      acc0 += av.w * c3[0]; acc1 += av.w * c3[1];
    }
    for (; jj < cl; ++jj) {
      int s2 = src_sh[wib][jj];
      float a = alpha_sh[wib][jj];
      uint v = *(const ushort*)(xl + (size_t)s2 * 128 + ch0);
      f32x2 c = __builtin_amdgcn_cvt_pk_f32_fp8((int)v, false);
      acc0 += a * c[0]; acc1 += a * c[1];
    }
    __builtin_amdgcn_wave_barrier();
  }
  for (int m = 1; m < 64; m <<= 1) den += __shfl_xor(den, m);
  float inv = 1.f / den;
  float* op = out + (size_t)nd * 128 + ch0;
  op[0] = acc0 * inv + bias[ch0 + 0];
  op[1] = acc1 * inv + bias[ch0 + 1];
}

// ---------------- mean pool (partial sums + atomics) ----------------
__global__ void pool_kernel(const float* __restrict__ h, float* __restrict__ g, int n) {
  int c = threadIdx.x;                 // 128 threads
  float acc = 0.f;
  for (int r = blockIdx.x; r < n; r += gridDim.x) acc += h[(size_t)r * 128 + c];
  atomicAdd(&g[c], acc);
}

// ---------------- final MLP ----------------
__global__ void mlp_kernel(const float* __restrict__ g, const float* __restrict__ Wm1,
                           const float* __restrict__ bm1, const float* __restrict__ Wm2,
                           const float* __restrict__ bm2, float* __restrict__ out,
                           float invn) {
  __shared__ float gs[128];
  __shared__ float hs[64];
  int t = threadIdx.x;                 // 64 threads
  gs[t] = g[t] * invn;
  gs[t + 64] = g[t + 64] * invn;
  __syncthreads();
  float acc = bm1[t];
  for (int c = 0; c < 128; ++c) acc += gs[c] * Wm1[c * 64 + t];
  hs[t] = fmaxf(acc, 0.f);
  __syncthreads();
  if (t == 0) {
    float o = bm2[0];
    for (int j = 0; j < 64; ++j) o += hs[j] * Wm2[j];
    out[0] = o;
  }
}

// ---------------------------------------------------------------------------
extern "C" void kernel_launch(void* const* d_in, const int* in_sizes, int n_in,
                              void* d_out, int out_size, void* d_ws, size_t ws_size,
                              hipStream_t stream) {
  const float* x   = (const float*)d_in[0];
  const int*   ei  = (const int*)d_in[1];
  const float* W0  = (const float*)d_in[2];
  const float* as0 = (const float*)d_in[3];
  const float* ad0 = (const float*)d_in[4];
  const float* b0  = (const float*)d_in[5];
  const float* W1  = (const float*)d_in[6];
  const float* as1 = (const float*)d_in[7];
  const float* ad1 = (const float*)d_in[8];
  const float* b1  = (const float*)d_in[9];
  const float* W2  = (const float*)d_in[10];
  const float* as2 = (const float*)d_in[11];
  const float* ad2 = (const float*)d_in[12];
  const float* b2  = (const float*)d_in[13];
  const float* Wm1 = (const float*)d_in[14];
  const float* bm1 = (const float*)d_in[15];
  const float* Wm2 = (const float*)d_in[16];
  const float* bm2 = (const float*)d_in[17];

  const int N = in_sizes[0] / 128;     // 20000
  const int E = in_sizes[1] / 2;       // 320000
  const int ET = E + N;                // with self loops

  // workspace layout
  ushort* hb  = (ushort*)d_ws;                        // N*512 bf16 (h)
  unsigned char* xlb = (unsigned char*)(hb + (size_t)N * 512);  // N*512 fp8 xl
  float*  h2  = (float*)(xlb + (size_t)N * 512);      // N*128 fp32 (pool input)
  float*  asn = h2 + (size_t)N * 128;                 // N*4
  float*  adn = asn + (size_t)N * 4;                  // N*4
  float*  g   = adn + (size_t)N * 4;                  // 128 pool accumulator
  int* counts = (int*)(g + 128);                      // N
  int* cursor = counts + N;                           // N
  int* offs   = cursor + N;                           // N+1
  int* srcs   = offs + N + 1;                         // ET
  int* parts  = srcs + ET;                            // 1024 scan partials
  ushort* w0h = (ushort*)(((uintptr_t)(parts + 1024) + 63) & ~(uintptr_t)63);
  ushort* w0l = w0h + 512 * 128;
  ushort* w1h = w0l + 512 * 128;
  ushort* w1l = w1h + 512 * 512;
  ushort* w2h = w1l + 512 * 512;
  ushort* w2l = w2h + 128 * 512;

  // zero pool accumulator + counts + cursor (contiguous)
  hipMemsetAsync(g, 0, (size_t)(128 + 2 * N) * sizeof(int), stream);

  wsplit_all_kernel<<<(98304 + 255) / 256, 256, 0, stream>>>(
      W0, W1, W2, w0h, w0l, w1h, w1l, w2h, w2l);

  // CSR by dst (multi-block scan)
  int ebl = (ET + 255) / 256;
  int nb = (N + 255) / 256;
  count_kernel<<<ebl, 256, 0, stream>>>(ei, counts, E, N);
  scan1_kernel<<<nb, 256, 0, stream>>>(counts, parts, N);
  scan2_kernel<<<1, 1024, 0, stream>>>(parts, nb);
  scan3_kernel<<<nb, 256, 0, stream>>>(counts, parts, offs, N);
  scatter_kernel<<<ebl, 256, 0, stream>>>(ei, offs, cursor, srcs, E, N);

  int nwb4 = (N + 3) / 4;              // 4 nodes/block
  int rsn = (N + 63) / 64;             // 313 row strips
  int rsp = ((rsn + 7) / 8) * 8;       // 320 (pad to x8 for swizzle)
  int blk01 = rsp * 4;                 // NC=4
  int blk2 = rsp;                      // NC=1

  // layer 0: fp32 x -> xlb (fp8) + stats
  gemm_f32a_kernel<4><<<blk01, 256, 0, stream>>>(x, w0h, w0l, xlb, as0, ad0,
                                                 asn, adn, N, 128);
  agg4_kernel<<<nwb4, 256, 0, stream>>>(xlb, asn, adn, offs, srcs, b0, hb, N);

  // layer 1: bf16 h0 -> xlb (fp8) + stats
  gemm_bf16a_kernel<4><<<blk01, 256, 0, stream>>>(hb, w1h, w1l, xlb, as1, ad1,
                                                  asn, adn, N, 512);
  agg4_kernel<<<nwb4, 256, 0, stream>>>(xlb, asn, adn, offs, srcs, b1, hb, N);

  // layer 2: bf16 h1 -> xlb (fp8, N*128) + stats; agg1 -> h2 fp32
  gemm_bf16a_kernel<1><<<blk2, 256, 0, stream>>>(hb, w2h, w2l, xlb, as2, ad2,
                                                 asn, adn, N, 512);
  agg1_kernel<<<nwb4, 256, 0, stream>>>(xlb, asn, adn, offs, srcs, b2, h2, N);

  // mean pool + MLP
  pool_kernel<<<128, 128, 0, stream>>>(h2, g, N);
  mlp_kernel<<<1, 64, 0, stream>>>(g, Wm1, bm1, Wm2, bm2, (float*)d_out, 1.0f / (float)N);
}